// Round 15
// baseline (302.238 us; speedup 1.0000x reference)
//
#include <hip/hip_runtime.h>
#include <hip/hip_bf16.h>

#define QLEN 512
#define MLEN 512
#define KLEN 1024
#define BSZ 8
#define DM 1024
#define NH 16
#define DH 64
#define DI 4096
#define NEGF (-1e30f)
#define HM_PART ((size_t)8388608)   // 128*1024*64 u16 per Q/K/V part

typedef unsigned short u16;
typedef __attribute__((ext_vector_type(8))) short short8;
typedef __attribute__((ext_vector_type(4))) short s16x4;
typedef __attribute__((ext_vector_type(4))) float f32x4;
typedef __attribute__((ext_vector_type(4))) unsigned int u32x4;

__device__ __forceinline__ float bf2f(u16 u) {
    union { unsigned i; float f; } x; x.i = ((unsigned)u) << 16; return x.f;
}
__device__ __forceinline__ u16 f2bf(float f) {
    __hip_bfloat16 h = __float2bfloat16(f);
    return *reinterpret_cast<u16*>(&h);
}
__device__ __forceinline__ float4 ldg4(const float* p) {
    return *reinterpret_cast<const float4*>(p);
}
// async global->LDS DMA, 16B per lane; LDS dest = wave-uniform base (+ lane*16 by HW)
__device__ __forceinline__ void gload16(const void* g, void* l) {
    __builtin_amdgcn_global_load_lds(
        (const __attribute__((address_space(1))) void*)g,
        (__attribute__((address_space(3))) void*)l, 16, 0, 0);
}

// ---------------- fused casts: mems|w -> catB, r -> rB -----------------------
__global__ __launch_bounds__(256) void cast_all(
    const float* __restrict__ mems, const float* __restrict__ w,
    const float* __restrict__ r, u16* __restrict__ catB, u16* __restrict__ rB)
{
    int idx = (blockIdx.x * 256 + threadIdx.x) * 4;
    const float* src;
    u16* dst;
    if (idx < 8388608) {   // catB: mems (first 4M elems) then w
        src = (idx < 4194304) ? (mems + idx) : (w + idx - 4194304);
        dst = catB + idx;
    } else {
        int i2 = idx - 8388608;
        if (i2 >= 1048576) return;
        src = r + i2;
        dst = rB + i2;
    }
    float4 v = ldg4(src);
    u16 o[4] = { f2bf(v.x), f2bf(v.y), f2bf(v.z), f2bf(v.w) };
    *reinterpret_cast<uint2*>(dst) = *reinterpret_cast<uint2*>(o);
}

// ---------------- fused weight transposes: 5 matrices in one launch ----------
__device__ __forceinline__ void tr32(
    const float* __restrict__ W, u16* __restrict__ WT, int K, int N, int k0, int n0)
{
    __shared__ float tile[32][33];
    const int tx = threadIdx.x & 31, ty = threadIdx.x >> 5;
    #pragma unroll
    for (int j = 0; j < 4; ++j)
        tile[ty + j * 8][tx] = W[(size_t)(k0 + ty + j * 8) * N + n0 + tx];
    __syncthreads();
    #pragma unroll
    for (int j = 0; j < 4; ++j)
        WT[(size_t)(n0 + ty + j * 8) * K + k0 + tx] = f2bf(tile[tx][ty + j * 8]);
}

__global__ __launch_bounds__(256) void transpose_all(
    const float* __restrict__ w_qkv, u16* __restrict__ qkvT,
    const float* __restrict__ w_r,   u16* __restrict__ wrT,
    const float* __restrict__ w_o,   u16* __restrict__ woT,
    const float* __restrict__ ffw1,  u16* __restrict__ f1T,
    const float* __restrict__ ffw2,  u16* __restrict__ f2T)
{
    int id = blockIdx.x;
    if (id < 3072)       { int l = id;        tr32(w_qkv, qkvT, 1024, 3072, (l / 96) * 32, (l % 96) * 32); }
    else if (id < 4096)  { int l = id - 3072; tr32(w_r,   wrT,  1024, 1024, (l / 32) * 32, (l % 32) * 32); }
    else if (id < 5120)  { int l = id - 4096; tr32(w_o,   woT,  1024, 1024, (l / 32) * 32, (l % 32) * 32); }
    else if (id < 9216)  { int l = id - 5120; tr32(ffw1,  f1T,  1024, 4096, (l / 128) * 32, (l % 128) * 32); }
    else                 { int l = id - 9216; tr32(ffw2,  f2T,  4096, 1024, (l / 32) * 32, (l % 32) * 32); }
}

// ---------------- V transpose: V_hm[(b,h)][key][d] -> Vg[(b,h)][d][key] ------
__global__ __launch_bounds__(256) void v_transpose(
    const u16* __restrict__ Vhm, u16* __restrict__ Vg)
{
    const int bn = blockIdx.x;            // b*16+n
    const int kt = blockIdx.y;            // 64-key tile
    const int t = threadIdx.x;
    __shared__ u16 L[64 * 64];            // [key][d], col-swizzled

    #pragma unroll
    for (int rep = 0; rep < 2; ++rep) {
        int idx = t + rep * 256;
        int key = idx >> 3, dc = (idx & 7) * 8;
        short8 v = *reinterpret_cast<const short8*>(
            &Vhm[((size_t)bn * 1024 + kt * 64 + key) * 64 + dc]);
        *reinterpret_cast<short8*>((char*)L + key * 128 + ((dc * 2) ^ ((key & 7) << 4))) = v;
    }
    __syncthreads();
    #pragma unroll
    for (int rep = 0; rep < 2; ++rep) {
        int idx = t + rep * 256;
        int d = idx >> 3, kc = (idx & 7) * 8;
        short8 o;
        #pragma unroll
        for (int e = 0; e < 8; ++e)
            o[e] = *(const short*)((char*)L + (kc + e) * 128 + ((d * 2) ^ (((kc + e) & 7) << 4)));
        *reinterpret_cast<short8*>(&Vg[((size_t)(bn * 64 + d)) * KLEN + kt * 64 + kc]) = o;
    }
}

// ---------------- bf16 MFMA GEMM (m97 structure, 128x128): rhk, w_o ----------
// OUT: 0 = fp32 flat, 1 = bf16 flat, 3 = bf16 head-major [n][row][d] (rhk)
template<bool BIAS, bool RELU, int OUT>
__global__ __launch_bounds__(256) void gemm_mfma(
    const u16* __restrict__ A, const u16* __restrict__ BT,
    const float* __restrict__ bias,
    float* __restrict__ Cf, u16* __restrict__ Cb,
    int M, int N, int K, int lda, int ldb)
{
    __shared__ u16 As[128 * 64];
    __shared__ u16 Bs[128 * 64];
    const int bm = blockIdx.y * 128, bn = blockIdx.x * 128;
    const int z = blockIdx.z;
    A  += (size_t)z * K;
    BT += (size_t)z * K;
    const size_t zoff = (size_t)z * M * N;
    const int t = threadIdx.x;
    const int w = t >> 6, l = t & 63, lg = l >> 4, lq = l & 15;
    const int wm = (w >> 1) * 64, wn = (w & 1) * 64;
    const int r8 = l >> 3, slot = l & 7;
    const int gcol = (slot * 16) ^ (r8 << 4);

    f32x4 acc[4][4];
    #pragma unroll
    for (int x = 0; x < 4; ++x)
        #pragma unroll
        for (int y = 0; y < 4; ++y)
            acc[x][y] = (f32x4){0.f, 0.f, 0.f, 0.f};

    const int swzr = (lq & 7) << 4;

    for (int k0 = 0; k0 < K; k0 += 64) {
        __syncthreads();
        #pragma unroll
        for (int it = 0; it < 4; ++it) {
            const int base_row = w * 8 + it * 32;
            gload16((const char*)A + (((size_t)(bm + base_row + r8) * lda + k0) << 1) + gcol,
                    (char*)As + base_row * 128);
            gload16((const char*)BT + (((size_t)(bn + base_row + r8) * ldb + k0) << 1) + gcol,
                    (char*)Bs + base_row * 128);
        }
        __syncthreads();
        #pragma unroll
        for (int ks = 0; ks < 2; ++ks) {
            const int cb = (ks * 64 + 16 * lg) ^ swzr;
            short8 af[4], bf_[4];
            #pragma unroll
            for (int x = 0; x < 4; ++x)
                af[x] = *reinterpret_cast<const short8*>((char*)As + (wm + 16 * x + lq) * 128 + cb);
            #pragma unroll
            for (int y = 0; y < 4; ++y)
                bf_[y] = *reinterpret_cast<const short8*>((char*)Bs + (wn + 16 * y + lq) * 128 + cb);
            #pragma unroll
            for (int x = 0; x < 4; ++x)
                #pragma unroll
                for (int y = 0; y < 4; ++y)
                    acc[x][y] = __builtin_amdgcn_mfma_f32_16x16x32_bf16(af[x], bf_[y], acc[x][y], 0, 0, 0);
        }
    }
    const int nn = ((bn + wn) >> 6) & 15;   // head index (OUT==3)
    #pragma unroll
    for (int x = 0; x < 4; ++x) {
        #pragma unroll
        for (int y = 0; y < 4; ++y) {
            const int col = bn + wn + 16 * y + lq;
            #pragma unroll
            for (int r = 0; r < 4; ++r) {
                const int row = bm + wm + 16 * x + 4 * lg + r;
                float v = acc[x][y][r];
                if constexpr (BIAS) { if (z == 0) v += bias[col]; }
                if constexpr (RELU) v = fmaxf(v, 0.f);
                if constexpr (OUT == 0) Cf[zoff + (size_t)row * N + col] = v;
                else if constexpr (OUT == 1) Cb[zoff + (size_t)row * N + col] = f2bf(v);
                else  // OUT == 3: rhk head-major [n][row][d]
                    Cb[((size_t)nn * 1024 + row) * 64 + 16 * y + lq] = f2bf(v);
            }
        }
    }
}

// ---------------- deep-pipeline bf16 MFMA GEMM (round-6 form, proven): ff2 ---
template<bool BIAS, bool RELU, int OUT>
__global__ __launch_bounds__(512, 2) void gemm_deep(
    const u16* __restrict__ A, const u16* __restrict__ BT,
    const float* __restrict__ bias,
    float* __restrict__ Cf, u16* __restrict__ Cb,
    int M, int N, int K, int lda, int ldb)
{
    __shared__ u16 lds[3 * 24576];        // 3 x (A 256x64 + B 128x64) = 144 KB
    const int bm = blockIdx.y * 256, bn = blockIdx.x * 128;
    const int z = blockIdx.z;
    A  += (size_t)z * K;
    BT += (size_t)z * K;
    const size_t zoff = (size_t)z * M * N;
    const int t = threadIdx.x;            // 0..511
    const int w = t >> 6, l = t & 63, lg = l >> 4, lq = l & 15;
    const int wm = (w >> 1) * 64;
    const int wn = (w & 1) * 64;
    const int srow = t >> 3, slot = t & 7;
    const int gcol = (slot * 16) ^ ((srow & 7) << 4);
    const int swzr = (lq & 7) << 4;

    auto stage_tile = [&](int kt, int buf) {
        const int k0 = kt * 64;
        char* Ab = (char*)lds + buf * 49152 + w * 1024;
        char* Bb = (char*)lds + buf * 49152 + 32768 + w * 1024;
        #pragma unroll
        for (int i = 0; i < 4; ++i)
            gload16((const char*)A + (((size_t)(bm + i * 64 + srow) * lda + k0) << 1) + gcol,
                    Ab + i * 8192);
        #pragma unroll
        for (int i = 0; i < 2; ++i)
            gload16((const char*)BT + (((size_t)(bn + i * 64 + srow) * ldb + k0) << 1) + gcol,
                    Bb + i * 8192);
    };

    f32x4 acc[4][4];
    #pragma unroll
    for (int x = 0; x < 4; ++x)
        #pragma unroll
        for (int y = 0; y < 4; ++y)
            acc[x][y] = (f32x4){0.f, 0.f, 0.f, 0.f};

    const int NT = K >> 6;
    stage_tile(0, 0);
    stage_tile(1, 1);

    for (int kt = 0; kt < NT; ++kt) {
        if (kt < NT - 1) asm volatile("s_waitcnt vmcnt(6)" ::: "memory");
        else             asm volatile("s_waitcnt vmcnt(0)" ::: "memory");
        __builtin_amdgcn_s_barrier();
        __builtin_amdgcn_sched_barrier(0);
        if (kt + 2 < NT) stage_tile(kt + 2, (kt + 2) % 3);

        const char* Ab = (const char*)lds + (kt % 3) * 49152;
        const char* Bb = Ab + 32768;
        #pragma unroll
        for (int ks = 0; ks < 2; ++ks) {
            const int cb = (ks * 64 + 16 * lg) ^ swzr;
            short8 af[4], bf_[4];
            #pragma unroll
            for (int x = 0; x < 4; ++x)
                af[x] = *reinterpret_cast<const short8*>(Ab + (wm + 16 * x + lq) * 128 + cb);
            #pragma unroll
            for (int y = 0; y < 4; ++y)
                bf_[y] = *reinterpret_cast<const short8*>(Bb + (wn + 16 * y + lq) * 128 + cb);
            __builtin_amdgcn_s_setprio(1);
            #pragma unroll
            for (int x = 0; x < 4; ++x)
                #pragma unroll
                for (int y = 0; y < 4; ++y)
                    acc[x][y] = __builtin_amdgcn_mfma_f32_16x16x32_bf16(af[x], bf_[y], acc[x][y], 0, 0, 0);
            __builtin_amdgcn_s_setprio(0);
        }
    }

    #pragma unroll
    for (int x = 0; x < 4; ++x) {
        #pragma unroll
        for (int y = 0; y < 4; ++y) {
            const int col = bn + wn + 16 * y + lq;
            #pragma unroll
            for (int r = 0; r < 4; ++r) {
                const int row = bm + wm + 16 * x + 4 * lg + r;
                float v = acc[x][y][r];
                if constexpr (BIAS) { if (z == 0) v += bias[col]; }
                if constexpr (RELU) v = fmaxf(v, 0.f);
                if constexpr (OUT == 0) Cf[zoff + (size_t)row * N + col] = v;
                else Cb[zoff + (size_t)row * N + col] = f2bf(v);
            }
        }
    }
}

// ---------------- 256x256 counted-vmcnt + read-ahead GEMM (round-15 fixed) ---
// MFMA phase order (mh0,ks0),(mh0,ks1),(mh1,ks0),(mh1,ks1) so that phase-0
// reads touch ONLY units u0-u2 (visible after ph0's vmcnt(2)); the u3 reads
// (a10,a11) happen in ph1 after u3's vmcnt. ds_read issue order is pinned by
// sched_barrier(0) between read groups, making counted lgkmcnt FIFO-sound:
//   ph0: vmcnt(2);bar; rd bk0|a00|bk1|a01(16); stage u0'; lgkm(8)->bk0,a00; MFMA(a00,bk0)
//   ph1: vmcnt(2/0);bar; rd a10|a11(8);        stage u1'; lgkm(8)->bk1,a01; MFMA(a01,bk1)
//   ph2: bar;                                   stage u2'; lgkm(4)->a10;     MFMA(a10,bk0)
//   ph3: bar;                                   stage u3'; lgkm(0)->a11;     MFMA(a11,bk1)
// OUT: 1 = bf16 flat; 2 = QKV head-major with Q-skip (320-block grid).
template<bool BIAS, bool RELU, int OUT>
__global__ __launch_bounds__(512, 2) void gemm256(
    const u16* __restrict__ A, const u16* __restrict__ BT,
    const float* __restrict__ bias, u16* __restrict__ Cb,
    int N, int K, int lda, int ldb, int nbx)
{
    __shared__ u16 lds[2 * 32768];        // 2 x (A 256x64 + B 256x64) = 128 KB
    int bm, bn;
    if constexpr (OUT == 2) {             // QKV with Q-skip
        const int id = blockIdx.x;
        if (id < 64) { bm = 4096 + (id >> 2) * 256; bn = (id & 3) * 256; }
        else         { int j = id - 64; bm = (j >> 3) * 256; bn = 1024 + (j & 7) * 256; }
    } else {
        bm = (blockIdx.x / nbx) * 256; bn = (blockIdx.x % nbx) * 256;
    }
    const int t = threadIdx.x;            // 0..511
    const int w = t >> 6, l = t & 63, lg = l >> 4, lq = l & 15;
    const int wm = (w >> 2) * 128;        // 2 M-groups of 128
    const int wn = (w & 3) * 64;          // 4 N-groups of 64
    const int srow = t >> 3, slot = t & 7;
    const int gcol = (slot * 16) ^ ((srow & 7) << 4);
    const int swzr = (lq & 7) << 4;

    auto stage_unit = [&](int kt, char* buf, int u) {
        const int k0 = kt * 64;
        if (u < 2) {            // B row-groups {2u, 2u+1}
            #pragma unroll
            for (int i = 0; i < 2; ++i) {
                int g = u * 2 + i;
                gload16((const char*)BT + (((size_t)(bn + g * 64 + srow) * ldb + k0) << 1) + gcol,
                        buf + 32768 + g * 8192 + w * 1024);
            }
        } else {                // A row-groups {u-2, u}: u2={0,2} (mh0), u3={1,3} (mh1)
            #pragma unroll
            for (int i = 0; i < 2; ++i) {
                int g = (u - 2) + i * 2;
                gload16((const char*)A + (((size_t)(bm + g * 64 + srow) * lda + k0) << 1) + gcol,
                        buf + g * 8192 + w * 1024);
            }
        }
    };

    f32x4 acc[8][4];
    #pragma unroll
    for (int m = 0; m < 8; ++m)
        #pragma unroll
        for (int y = 0; y < 4; ++y)
            acc[m][y] = (f32x4){0.f, 0.f, 0.f, 0.f};

    const int NT = K >> 6;
    #pragma unroll
    for (int u = 0; u < 4; ++u) stage_unit(0, (char*)lds, u);

    for (int kt = 0; kt < NT; ++kt) {
        const char* Ab = (const char*)lds + (kt & 1) * 65536;
        const char* Bb = Ab + 32768;
        char* nbuf = (char*)lds + ((kt + 1) & 1) * 65536;
        const bool pf = (kt + 1 < NT);
        const int cb0 = (16 * lg) ^ swzr;
        const int cb1 = (64 + 16 * lg) ^ swzr;

        short8 bk0[4], bk1[4], a00[4], a01[4], a10[4], a11[4];

        // ---- phase 0: (mh0, ks0); reads touch only u0-u2
        asm volatile("s_waitcnt vmcnt(2)" ::: "memory");
        __builtin_amdgcn_s_barrier();
        __builtin_amdgcn_sched_barrier(0);
        #pragma unroll
        for (int y = 0; y < 4; ++y)
            bk0[y] = *reinterpret_cast<const short8*>(Bb + (wn + 16 * y + lq) * 128 + cb0);
        __builtin_amdgcn_sched_barrier(0);
        #pragma unroll
        for (int x = 0; x < 4; ++x)
            a00[x] = *reinterpret_cast<const short8*>(Ab + (wm + 16 * x + lq) * 128 + cb0);
        __builtin_amdgcn_sched_barrier(0);
        #pragma unroll
        for (int y = 0; y < 4; ++y)
            bk1[y] = *reinterpret_cast<const short8*>(Bb + (wn + 16 * y + lq) * 128 + cb1);
        __builtin_amdgcn_sched_barrier(0);
        #pragma unroll
        for (int x = 0; x < 4; ++x)
            a01[x] = *reinterpret_cast<const short8*>(Ab + (wm + 16 * x + lq) * 128 + cb1);
        __builtin_amdgcn_sched_barrier(0);
        if (pf) stage_unit(kt + 1, nbuf, 0);
        asm volatile("s_waitcnt lgkmcnt(8)" ::: "memory");
        __builtin_amdgcn_sched_barrier(0);
        __builtin_amdgcn_s_setprio(1);
        #pragma unroll
        for (int x = 0; x < 4; ++x)
            #pragma unroll
            for (int y = 0; y < 4; ++y)
                acc[x][y] = __builtin_amdgcn_mfma_f32_16x16x32_bf16(a00[x], bk0[y], acc[x][y], 0, 0, 0);
        __builtin_amdgcn_s_setprio(0);

        // ---- phase 1: (mh0, ks1); u3 now resident after this vmcnt
        if (pf) asm volatile("s_waitcnt vmcnt(2)" ::: "memory");
        else    asm volatile("s_waitcnt vmcnt(0)" ::: "memory");
        __builtin_amdgcn_s_barrier();
        __builtin_amdgcn_sched_barrier(0);
        #pragma unroll
        for (int x = 0; x < 4; ++x)
            a10[x] = *reinterpret_cast<const short8*>(Ab + (wm + 64 + 16 * x + lq) * 128 + cb0);
        __builtin_amdgcn_sched_barrier(0);
        #pragma unroll
        for (int x = 0; x < 4; ++x)
            a11[x] = *reinterpret_cast<const short8*>(Ab + (wm + 64 + 16 * x + lq) * 128 + cb1);
        __builtin_amdgcn_sched_barrier(0);
        if (pf) stage_unit(kt + 1, nbuf, 1);
        asm volatile("s_waitcnt lgkmcnt(8)" ::: "memory");
        __builtin_amdgcn_sched_barrier(0);
        __builtin_amdgcn_s_setprio(1);
        #pragma unroll
        for (int x = 0; x < 4; ++x)
            #pragma unroll
            for (int y = 0; y < 4; ++y)
                acc[x][y] = __builtin_amdgcn_mfma_f32_16x16x32_bf16(a01[x], bk1[y], acc[x][y], 0, 0, 0);
        __builtin_amdgcn_s_setprio(0);

        // ---- phase 2: (mh1, ks0)
        __builtin_amdgcn_s_barrier();
        __builtin_amdgcn_sched_barrier(0);
        if (pf) stage_unit(kt + 1, nbuf, 2);
        asm volatile("s_waitcnt lgkmcnt(4)" ::: "memory");
        __builtin_amdgcn_sched_barrier(0);
        __builtin_amdgcn_s_setprio(1);
        #pragma unroll
        for (int x = 0; x < 4; ++x)
            #pragma unroll
            for (int y = 0; y < 4; ++y)
                acc[4 + x][y] = __builtin_amdgcn_mfma_f32_16x16x32_bf16(a10[x], bk0[y], acc[4 + x][y], 0, 0, 0);
        __builtin_amdgcn_s_setprio(0);

        // ---- phase 3: (mh1, ks1)
        __builtin_amdgcn_s_barrier();
        __builtin_amdgcn_sched_barrier(0);
        if (pf) stage_unit(kt + 1, nbuf, 3);
        asm volatile("s_waitcnt lgkmcnt(0)" ::: "memory");
        __builtin_amdgcn_sched_barrier(0);
        __builtin_amdgcn_s_setprio(1);
        #pragma unroll
        for (int x = 0; x < 4; ++x)
            #pragma unroll
            for (int y = 0; y < 4; ++y)
                acc[4 + x][y] = __builtin_amdgcn_mfma_f32_16x16x32_bf16(a11[x], bk1[y], acc[4 + x][y], 0, 0, 0);
        __builtin_amdgcn_s_setprio(0);
    }

    #pragma unroll
    for (int m = 0; m < 8; ++m) {
        #pragma unroll
        for (int y = 0; y < 4; ++y) {
            const int col = bn + wn + 16 * y + lq;
            #pragma unroll
            for (int r = 0; r < 4; ++r) {
                const int row = bm + wm + m * 16 + 4 * lg + r;
                float v = acc[m][y][r];
                if constexpr (BIAS) v += bias[col];
                if constexpr (RELU) v = fmaxf(v, 0.f);
                if constexpr (OUT == 2) {   // head-major: row = key*8+b
                    const int part = col >> 10, nn = (col >> 6) & 15;
                    Cb[(size_t)part * HM_PART
                       + ((size_t)((row & 7) * 16 + nn) * 1024 + (row >> 3)) * 64
                       + (col & 63)] = f2bf(v);
                } else {
                    Cb[(size_t)row * N + col] = f2bf(v);
                }
            }
        }
    }
}

// ---------------- MFMA flash relative attention (round-13 form, proven) ------
__global__ __launch_bounds__(512, 4) void attn_mfma(
    const u16* __restrict__ Hm,      // head-major Q|K|V, parts of [(b,h)][tok][d]
    const u16* __restrict__ Vg,      // bf16 [(b,h)][DH][KLEN]
    const u16* __restrict__ rhm,     // bf16 head-major [h][o][d]
    const float* __restrict__ rwb, const float* __restrict__ rrb,
    u16* __restrict__ vec)           // bf16 [QLEN*BSZ][NH*DH]
{
    const int bnidx = blockIdx.x;                // b*16+n
    const int b = bnidx >> 4;
    const int n = bnidx & 15;
    const int i0 = (3 - blockIdx.y) * 128;       // long blocks first
    const int t = threadIdx.x;
    const int w = t >> 6;                        // 0..7
    const int l = t & 63;
    const int lg = l >> 4, lq = l & 15;
    const int r8 = l >> 3, sl = l & 7;

    const u16* Qh = Hm;
    const u16* Kh = Hm + HM_PART;

    __shared__ u16 Ks[64 * 64];
    __shared__ u16 Vt[64 * 64];
    __shared__ u16 Rs[192 * 64];
    __shared__ u16 SbO[8 * 16 * 84];
    __shared__ u16 Ps[8 * 16 * 64];

    u16* SbW = SbO + w * 16 * 84;
    u16* PsW = Ps + w * 16 * 64;
    const int swzr = (lq & 7) << 4;
    const int stg_swz = (sl * 16) ^ (r8 << 4);
    const int lofs = l * 16;
    const int rbase = 384 - i0;
    const int ntiles = i0 / 64 + 10;

    auto kSrc = [&](int tile) {
        return (const char*)Kh + (((size_t)bnidx * 1024 + (tile << 6) + w * 8 + r8) * 64 << 1) + stg_swz;
    };
    auto vSrc = [&](int tile) {
        return (const char*)Vg + ((((size_t)bnidx * 64 + w * 8 + r8) * KLEN + (tile << 6)) << 1) + stg_swz;
    };
    auto rSrc = [&](int g) {
        int o = rbase + g * 64 + w * 8 + r8;
        o = o > (KLEN - 1) ? (KLEN - 1) : o;
        return (const char*)rhm + (((size_t)n * 1024 + o) * 64 << 1) + stg_swz;
    };

    // Q fragments with 1/sqrt(d)=0.125 folded in
    short8 qw[2], qr[2];
    {
        const size_t qbase = ((size_t)bnidx * 1024 + MLEN + i0 + 16 * w + lq) * 64;
        #pragma unroll
        for (int ks = 0; ks < 2; ++ks) {
            short8 qv = *reinterpret_cast<const short8*>(&Qh[qbase + ks * 32 + 8 * lg]);
            short8 xw, xr;
            #pragma unroll
            for (int e = 0; e < 8; ++e) {
                float f = bf2f((u16)qv[e]);
                int d = ks * 32 + 8 * lg + e;
                xw[e] = (short)f2bf((f + rwb[n * 64 + d]) * 0.125f);
                xr[e] = (short)f2bf((f + rrb[n * 64 + d]) * 0.125f);
            }
            qw[ks] = xw; qr[ks] = xr;
        }
    }

    float m_run = NEGF, l_run = 0.f;
    f32x4 acc[4];
    #pragma unroll
    for (int df = 0; df < 4; ++df) acc[df] = (f32x4){0.f, 0.f, 0.f, 0.f};

    const int s0 = 112 - 16 * w;

    // prologue: tile-0 staging into registers
    u32x4 kreg = *reinterpret_cast<const u32x4*>(kSrc(0));
    u32x4 vreg = *reinterpret_cast<const u32x4*>(vSrc(0));
    u32x4 rr0  = *reinterpret_cast<const u32x4*>(rSrc(0));
    u32x4 rr1  = *reinterpret_cast<const u32x4*>(rSrc(1));
    u32x4 rr2  = *reinterpret_cast<const u32x4*>(rSrc(2));

    for (int tile = 0; tile < ntiles; ++tile) {
        const int j0 = tile << 6;
        __builtin_amdgcn_s_barrier();            // all waves done reading prev tile
        __builtin_amdgcn_sched_barrier(0);
        *reinterpret_cast<u32x4*>((char*)Ks + w * 1024 + lofs) = kreg;
        *reinterpret_cast<u32x4*>((char*)Vt + w * 1024 + lofs) = vreg;
        if (tile == 0) {
            *reinterpret_cast<u32x4*>((char*)Rs + 0 * 8192 + w * 1024 + lofs) = rr0;
            *reinterpret_cast<u32x4*>((char*)Rs + 1 * 8192 + w * 1024 + lofs) = rr1;
            *reinterpret_cast<u32x4*>((char*)Rs + 2 * 8192 + w * 1024 + lofs) = rr2;
        } else {
            *reinterpret_cast<u32x4*>((char*)Rs + ((tile + 2) % 3) * 8192 + w * 1024 + lofs) = rr0;
        }
        if (tile + 1 < ntiles) {
            kreg = *reinterpret_cast<const u32x4*>(kSrc(tile + 1));
            vreg = *reinterpret_cast<const u32x4*>(vSrc(tile + 1));
            rr0  = *reinterpret_cast<const u32x4*>(rSrc(tile + 3));
        }
        asm volatile("s_waitcnt lgkmcnt(0)" ::: "memory");
        __builtin_amdgcn_s_barrier();            // all waves' ds_writes visible
        __builtin_amdgcn_sched_barrier(0);

        const int bmax = i0 + 16 * w + 15 + MLEN - j0;
        if (bmax < 0) continue;                  // per-wave skip; barriers balanced

        __builtin_amdgcn_s_setprio(1);
        #pragma unroll
        for (int ff = 0; ff < 5; ++ff) {
            const int olf = s0 + 16 * ff;
            const int srowb = ((tile + (olf >> 6)) % 3) * 64 + (olf & 63);
            f32x4 d = (f32x4){0.f, 0.f, 0.f, 0.f};
            #pragma unroll
            for (int ks = 0; ks < 2; ++ks) {
                short8 a = *reinterpret_cast<const short8*>(
                    (char*)Rs + (srowb + lq) * 128 + ((ks * 64 + 16 * lg) ^ swzr));
                d = __builtin_amdgcn_mfma_f32_16x16x32_bf16(a, qr[ks], d, 0, 0, 0);
            }
            s16x4 pk;
            #pragma unroll
            for (int r = 0; r < 4; ++r) pk[r] = (short)f2bf(d[r]);
            *reinterpret_cast<s16x4*>(&SbW[lq * 84 + 16 * ff + 4 * lg]) = pk;
        }
        f32x4 dac[4];
        #pragma unroll
        for (int f = 0; f < 4; ++f) {
            f32x4 d = (f32x4){0.f, 0.f, 0.f, 0.f};
            #pragma unroll
            for (int ks = 0; ks < 2; ++ks) {
                short8 a = *reinterpret_cast<const short8*>(
                    (char*)Ks + (16 * f + lq) * 128 + ((ks * 64 + 16 * lg) ^ swzr));
                d = __builtin_amdgcn_mfma_f32_16x16x32_bf16(a, qw[ks], d, 0, 0, 0);
            }
            dac[f] = d;
        }
        __builtin_amdgcn_s_setprio(0);

        const bool fullTile = (i0 + 16 * w + MLEN - j0) >= 63;
        float sv[4][4];
        float mx = NEGF;
        if (fullTile) {
            #pragma unroll
            for (int f = 0; f < 4; ++f)
                #pragma unroll
                for (int r = 0; r < 4; ++r) {
                    int k = 16 * f + 4 * lg + r;
                    float x = dac[f][r] + bf2f(SbW[lq * 84 + k - lq + 15]);
                    sv[f][r] = x;
                    mx = fmaxf(mx, x);
                }
        } else {
            const int bound = i0 + 16 * w + lq + MLEN - j0;
            #pragma unroll
            for (int f = 0; f < 4; ++f)
                #pragma unroll
                for (int r = 0; r < 4; ++r) {
                    int k = 16 * f + 4 * lg + r;
                    float x = (k <= bound)
                        ? dac[f][r] + bf2f(SbW[lq * 84 + k - lq + 15]) : NEGF;
                    sv[f][r] = x;
                    mx = fmaxf(mx, x);
                }
        }
        mx = fmaxf(mx, __shfl_xor(mx, 16));
        mx = fmaxf(mx, __shfl_xor(mx, 32));
        const bool defer = (__all(mx <= m_run + 8.0f) != 0);
        const float m_new = defer ? m_run : fmaxf(m_run, mx);
        float ps = 0.f;
        #pragma unroll
        for (int f = 0; f < 4; ++f) {
            s16x4 pk;
            #pragma unroll
            for (int r = 0; r < 4; ++r) {
                float p = __expf(sv[f][r] - m_new);
                ps += p;
                pk[r] = (short)f2bf(p);
            }
            *reinterpret_cast<s16x4*>(
                (char*)PsW + lq * 128 + (((4 * f + lg) ^ ((lq & 7) << 1)) << 3)) = pk;
        }
        ps += __shfl_xor(ps, 16);
        ps += __shfl_xor(ps, 32);
        if (defer) {
            l_run += ps;
        } else {
            float alpha = __expf(m_run - m_new);
            l_run = l_run * alpha + ps;
            m_run = m_new;
            float alr[4];
            #pragma unroll
            for (int r = 0; r < 4; ++r) alr[r] = __shfl(alpha, 20 * lg + r);
            #pragma unroll
            for (int df = 0; df < 4; ++df)
                #pragma unroll
                for (int r = 0; r < 4; ++r) acc[df][r] *= alr[r];
        }

        __builtin_amdgcn_s_setprio(1);
        #pragma unroll
        for (int df = 0; df < 4; ++df) {
            f32x4 a = acc[df];
            #pragma unroll
            for (int ks = 0; ks < 2; ++ks) {
                short8 pa = *reinterpret_cast<const short8*>(
                    (char*)PsW + lq * 128 + ((ks * 64 + 16 * lg) ^ swzr));
                short8 vb = *reinterpret_cast<const short8*>(
                    (char*)Vt + (16 * df + lq) * 128 + ((ks * 64 + 16 * lg) ^ swzr));
                a = __builtin_amdgcn_mfma_f32_16x16x32_bf16(pa, vb, a, 0, 0, 0);
            }
            acc[df] = a;
        }
        __builtin_amdgcn_s_setprio(0);
    }

    float inv[4];
    #pragma unroll
    for (int r = 0; r < 4; ++r) inv[r] = 1.f / __shfl(l_run, 20 * lg + r);
    #pragma unroll
    for (int df = 0; df < 4; ++df) {
        #pragma unroll
        for (int r = 0; r < 4; ++r) {
            const int il = 16 * w + 4 * lg + r;
            float o = acc[df][r] * inv[r];
            vec[((size_t)((i0 + il) * BSZ + b)) * DM + n * 64 + 16 * df + lq] = f2bf(o);
        }
    }
}

// ---------------- Residual + LayerNorm (1 or 2 extra fp32 residual streams) --
template<int NRES, bool WB>
__global__ __launch_bounds__(256) void ln_res_kernel(
    const float* __restrict__ x, const float* __restrict__ res,
    const float* __restrict__ res2,
    const float* __restrict__ g, const float* __restrict__ bta,
    float* __restrict__ out, u16* __restrict__ outb)
{
    const int row = blockIdx.x;
    const int t = threadIdx.x;
    const int lane = t & 63, wv = t >> 6;
    __shared__ float red0[4], red1[4];

    float4 a = ldg4(&x[(size_t)row * DM + t * 4]);
    float4 b = ldg4(&res[(size_t)row * DM + t * 4]);
    float v0 = a.x + b.x, v1 = a.y + b.y, v2 = a.z + b.z, v3 = a.w + b.w;
    if constexpr (NRES == 2) {
        float4 c = ldg4(&res2[(size_t)row * DM + t * 4]);
        v0 += c.x; v1 += c.y; v2 += c.z; v3 += c.w;
    }
    float s = v0 + v1 + v2 + v3;
    #pragma unroll
    for (int o = 32; o; o >>= 1) s += __shfl_xor(s, o);
    if (lane == 0) red0[wv] = s;
    __syncthreads();
    float mu = (red0[0] + red0[1] + red0[2] + red0[3]) * (1.f / DM);
    float d0 = v0 - mu, d1 = v1 - mu, d2 = v2 - mu, d3 = v3 - mu;
    float q = d0*d0 + d1*d1 + d2*d2 + d3*d3;
    #pragma unroll
    for (int o = 32; o; o >>= 1) q += __shfl_xor(q, o);
    if (lane == 0) red1[wv] = q;
    __syncthreads();
    float var = (red1[0] + red1[1] + red1[2] + red1[3]) * (1.f / DM);
    float rs = rsqrtf(var + 1e-5f);
    float4 gv = ldg4(&g[t * 4]);
    float4 bv = ldg4(&bta[t * 4]);
    float o0 = d0 * rs * gv.x + bv.x;
    float o1 = d1 * rs * gv.y + bv.y;
    float o2 = d2 * rs * gv.z + bv.z;
    float o3 = d3 * rs * gv.w + bv.w;
    float4 o4 = make_float4(o0, o1, o2, o3);
    *reinterpret_cast<float4*>(&out[(size_t)row * DM + t * 4]) = o4;
    if constexpr (WB) {
        u16 ob[4] = { f2bf(o0), f2bf(o1), f2bf(o2), f2bf(o3) };
        *reinterpret_cast<uint2*>(&outb[(size_t)row * DM + t * 4]) = *reinterpret_cast<uint2*>(ob);
    }
}

// ---------------- launch ------------------------------------------------------
extern "C" void kernel_launch(void* const* d_in, const int* in_sizes, int n_in,
                              void* d_out, int out_size, void* d_ws, size_t ws_size,
                              hipStream_t stream) {
    const float* w     = (const float*)d_in[0];
    const float* r     = (const float*)d_in[1];
    const float* mems  = (const float*)d_in[2];
    const float* w_qkv = (const float*)d_in[3];
    const float* w_r   = (const float*)d_in[4];
    const float* w_o   = (const float*)d_in[5];
    const float* rwb   = (const float*)d_in[6];
    const float* rrb   = (const float*)d_in[7];
    const float* ln1g  = (const float*)d_in[8];
    const float* ln1b  = (const float*)d_in[9];
    const float* ffw1  = (const float*)d_in[10];
    const float* ffb1  = (const float*)d_in[11];
    const float* ffw2  = (const float*)d_in[12];
    const float* ffb2  = (const float*)d_in[13];
    const float* ln2g  = (const float*)d_in[14];
    const float* ln2b  = (const float*)d_in[15];
    (void)in_sizes; (void)n_in; (void)out_size; (void)ws_size;

    char* p = (char*)d_ws;
    auto alloc = [&](size_t bytes) { char* q = p; p += (bytes + 255) & ~(size_t)255; return q; };
    u16* catB   = (u16*)alloc((size_t)8192 * 1024 * 2);   // reused as Vg after QKV GEMM
    u16* rB     = (u16*)alloc((size_t)1024 * 1024 * 2);
    u16* qkvT   = (u16*)alloc((size_t)3072 * 1024 * 2);
    u16* wrT    = (u16*)alloc((size_t)1024 * 1024 * 2);
    u16* woT    = (u16*)alloc((size_t)1024 * 1024 * 2);
    u16* f1T    = (u16*)alloc((size_t)4096 * 1024 * 2);
    u16* f2T    = (u16*)alloc((size_t)1024 * 4096 * 2);
    u16* headsHm= (u16*)alloc((size_t)3 * HM_PART * 2);   // reused as ff2[2] after attn
    u16* rhkHm  = (u16*)alloc((size_t)1024 * 1024 * 2);
    u16* vec    = (u16*)alloc((size_t)4096 * 1024 * 2);
    u16* hB     = (u16*)alloc((size_t)4096 * 1024 * 2);
    u16* ff1    = (u16*)alloc((size_t)4096 * 4096 * 2);   // doubles as attn_out[2] before ff1
    float* hF   = (float*)alloc((size_t)4096 * 1024 * 4);

    u16* Vg = catB;
    float* attn_out = (float*)ff1;
    float* ff2 = (float*)headsHm;
    float* outp = (float*)d_out;

    // fused casts + fused weight transposes
    cast_all<<<9216, 256, 0, stream>>>(mems, w, r, catB, rB);
    transpose_all<<<13312, 256, 0, stream>>>(w_qkv, qkvT, w_r, wrT, w_o, woT,
                                             ffw1, f1T, ffw2, f2T);

    // 1. heads = cat @ w_qkv -> head-major Q|K|V, Q computed only for tok>=512
    gemm256<false, false, 2><<<320, 512, 0, stream>>>(
        catB, qkvT, nullptr, headsHm, 3072, 1024, 1024, 1024, 0);
    // 2. V transpose (catB dead -> Vg aliases it); reads V_hm part
    v_transpose<<<dim3(128, 16), 256, 0, stream>>>(headsHm + 2 * HM_PART, Vg);
    // 3. rhk = r @ w_r -> head-major [h][o][d]
    gemm_mfma<false, false, 3><<<dim3(8, 8), 256, 0, stream>>>(
        rB, wrT, nullptr, nullptr, rhkHm, 1024, 1024, 1024, 1024, 1024);
    // 4. attention (T14 reg-staged prefetch)
    attn_mfma<<<dim3(BSZ * NH, QLEN / 128), 512, 0, stream>>>(
        headsHm, Vg, rhkHm, rwb, rrb, vec);
    // 5. attn_out = vec @ w_o, split-K x2 (128^2 kernel, fp32 partials)
    gemm_mfma<false, false, 0><<<dim3(8, 32, 2), 256, 0, stream>>>(
        vec, woT, nullptr, attn_out, nullptr, 4096, 1024, 512, 1024, 1024);
    // 6. h = LN(w + ao0 + ao1), keep fp32 + bf16
    ln_res_kernel<2, true><<<4096, 256, 0, stream>>>(
        w, attn_out, attn_out + (size_t)4096 * 1024, ln1g, ln1b, hF, hB);
    // 7. ff1 = relu(h @ ff_w1 + b1)  (read-ahead 256^2, fixed schedule)
    gemm256<true, true, 1><<<256, 512, 0, stream>>>(
        hB, f1T, ffb1, ff1, 4096, 1024, 1024, 1024, 16);
    // 8. ff2 = ff1 @ ff_w2 + b2, split-K x2 (proven deep kernel, fp32 partials)
    gemm_deep<true, false, 0><<<dim3(8, 16, 2), 512, 0, stream>>>(
        ff1, f2T, ffb2, ff2, nullptr, 4096, 1024, 2048, 4096, 4096);
    // 9. out = LN(h + ff2a + ff2b)
    ln_res_kernel<2, false><<<4096, 256, 0, stream>>>(
        hF, ff2, ff2 + (size_t)4096 * 1024, ln2g, ln2b, outp, nullptr);
}

// Round 16
// 299.770 us; speedup vs baseline: 1.0082x; 1.0082x over previous
//
#include <hip/hip_runtime.h>
#include <hip/hip_bf16.h>

#define QLEN 512
#define MLEN 512
#define KLEN 1024
#define BSZ 8
#define DM 1024
#define NH 16
#define DH 64
#define DI 4096
#define NEGF (-1e30f)
#define HM_PART ((size_t)8388608)   // 128*1024*64 u16 per Q/K/V part

typedef unsigned short u16;
typedef __attribute__((ext_vector_type(8))) short short8;
typedef __attribute__((ext_vector_type(4))) short s16x4;
typedef __attribute__((ext_vector_type(4))) float f32x4;
typedef __attribute__((ext_vector_type(4))) unsigned int u32x4;

__device__ __forceinline__ float bf2f(u16 u) {
    union { unsigned i; float f; } x; x.i = ((unsigned)u) << 16; return x.f;
}
__device__ __forceinline__ u16 f2bf(float f) {
    __hip_bfloat16 h = __float2bfloat16(f);
    return *reinterpret_cast<u16*>(&h);
}
__device__ __forceinline__ float4 ldg4(const float* p) {
    return *reinterpret_cast<const float4*>(p);
}
// async global->LDS DMA, 16B per lane; LDS dest = wave-uniform base (+ lane*16 by HW)
__device__ __forceinline__ void gload16(const void* g, void* l) {
    __builtin_amdgcn_global_load_lds(
        (const __attribute__((address_space(1))) void*)g,
        (__attribute__((address_space(3))) void*)l, 16, 0, 0);
}

// ---------------- fused casts: mems|w -> catB, r -> rB -----------------------
__global__ __launch_bounds__(256) void cast_all(
    const float* __restrict__ mems, const float* __restrict__ w,
    const float* __restrict__ r, u16* __restrict__ catB, u16* __restrict__ rB)
{
    int idx = (blockIdx.x * 256 + threadIdx.x) * 4;
    const float* src;
    u16* dst;
    if (idx < 8388608) {   // catB: mems (first 4M elems) then w
        src = (idx < 4194304) ? (mems + idx) : (w + idx - 4194304);
        dst = catB + idx;
    } else {
        int i2 = idx - 8388608;
        if (i2 >= 1048576) return;
        src = r + i2;
        dst = rB + i2;
    }
    float4 v = ldg4(src);
    u16 o[4] = { f2bf(v.x), f2bf(v.y), f2bf(v.z), f2bf(v.w) };
    *reinterpret_cast<uint2*>(dst) = *reinterpret_cast<uint2*>(o);
}

// ---------------- fused weight transposes: 5 matrices in one launch ----------
__device__ __forceinline__ void tr32(
    const float* __restrict__ W, u16* __restrict__ WT, int K, int N, int k0, int n0)
{
    __shared__ float tile[32][33];
    const int tx = threadIdx.x & 31, ty = threadIdx.x >> 5;
    #pragma unroll
    for (int j = 0; j < 4; ++j)
        tile[ty + j * 8][tx] = W[(size_t)(k0 + ty + j * 8) * N + n0 + tx];
    __syncthreads();
    #pragma unroll
    for (int j = 0; j < 4; ++j)
        WT[(size_t)(n0 + ty + j * 8) * K + k0 + tx] = f2bf(tile[tx][ty + j * 8]);
}

__global__ __launch_bounds__(256) void transpose_all(
    const float* __restrict__ w_qkv, u16* __restrict__ qkvT,
    const float* __restrict__ w_r,   u16* __restrict__ wrT,
    const float* __restrict__ w_o,   u16* __restrict__ woT,
    const float* __restrict__ ffw1,  u16* __restrict__ f1T,
    const float* __restrict__ ffw2,  u16* __restrict__ f2T)
{
    int id = blockIdx.x;
    if (id < 3072)       { int l = id;        tr32(w_qkv, qkvT, 1024, 3072, (l / 96) * 32, (l % 96) * 32); }
    else if (id < 4096)  { int l = id - 3072; tr32(w_r,   wrT,  1024, 1024, (l / 32) * 32, (l % 32) * 32); }
    else if (id < 5120)  { int l = id - 4096; tr32(w_o,   woT,  1024, 1024, (l / 32) * 32, (l % 32) * 32); }
    else if (id < 9216)  { int l = id - 5120; tr32(ffw1,  f1T,  1024, 4096, (l / 128) * 32, (l % 128) * 32); }
    else                 { int l = id - 9216; tr32(ffw2,  f2T,  4096, 1024, (l / 32) * 32, (l % 32) * 32); }
}

// ---------------- V transpose: V_hm[(b,h)][key][d] -> Vg[(b,h)][d][key] ------
__global__ __launch_bounds__(256) void v_transpose(
    const u16* __restrict__ Vhm, u16* __restrict__ Vg)
{
    const int bn = blockIdx.x;            // b*16+n
    const int kt = blockIdx.y;            // 64-key tile
    const int t = threadIdx.x;
    __shared__ u16 L[64 * 64];            // [key][d], col-swizzled

    #pragma unroll
    for (int rep = 0; rep < 2; ++rep) {
        int idx = t + rep * 256;
        int key = idx >> 3, dc = (idx & 7) * 8;
        short8 v = *reinterpret_cast<const short8*>(
            &Vhm[((size_t)bn * 1024 + kt * 64 + key) * 64 + dc]);
        *reinterpret_cast<short8*>((char*)L + key * 128 + ((dc * 2) ^ ((key & 7) << 4))) = v;
    }
    __syncthreads();
    #pragma unroll
    for (int rep = 0; rep < 2; ++rep) {
        int idx = t + rep * 256;
        int d = idx >> 3, kc = (idx & 7) * 8;
        short8 o;
        #pragma unroll
        for (int e = 0; e < 8; ++e)
            o[e] = *(const short*)((char*)L + (kc + e) * 128 + ((d * 2) ^ (((kc + e) & 7) << 4)));
        *reinterpret_cast<short8*>(&Vg[((size_t)(bn * 64 + d)) * KLEN + kt * 64 + kc]) = o;
    }
}

// ---------------- bf16 MFMA GEMM (m97 structure, 128x128): rhk, w_o ----------
// OUT: 0 = fp32 flat, 1 = bf16 flat, 3 = bf16 head-major [n][row][d] (rhk)
template<bool BIAS, bool RELU, int OUT>
__global__ __launch_bounds__(256) void gemm_mfma(
    const u16* __restrict__ A, const u16* __restrict__ BT,
    const float* __restrict__ bias,
    float* __restrict__ Cf, u16* __restrict__ Cb,
    int M, int N, int K, int lda, int ldb)
{
    __shared__ u16 As[128 * 64];
    __shared__ u16 Bs[128 * 64];
    const int bm = blockIdx.y * 128, bn = blockIdx.x * 128;
    const int z = blockIdx.z;
    A  += (size_t)z * K;
    BT += (size_t)z * K;
    const size_t zoff = (size_t)z * M * N;
    const int t = threadIdx.x;
    const int w = t >> 6, l = t & 63, lg = l >> 4, lq = l & 15;
    const int wm = (w >> 1) * 64, wn = (w & 1) * 64;
    const int r8 = l >> 3, slot = l & 7;
    const int gcol = (slot * 16) ^ (r8 << 4);

    f32x4 acc[4][4];
    #pragma unroll
    for (int x = 0; x < 4; ++x)
        #pragma unroll
        for (int y = 0; y < 4; ++y)
            acc[x][y] = (f32x4){0.f, 0.f, 0.f, 0.f};

    const int swzr = (lq & 7) << 4;

    for (int k0 = 0; k0 < K; k0 += 64) {
        __syncthreads();
        #pragma unroll
        for (int it = 0; it < 4; ++it) {
            const int base_row = w * 8 + it * 32;
            gload16((const char*)A + (((size_t)(bm + base_row + r8) * lda + k0) << 1) + gcol,
                    (char*)As + base_row * 128);
            gload16((const char*)BT + (((size_t)(bn + base_row + r8) * ldb + k0) << 1) + gcol,
                    (char*)Bs + base_row * 128);
        }
        __syncthreads();
        #pragma unroll
        for (int ks = 0; ks < 2; ++ks) {
            const int cb = (ks * 64 + 16 * lg) ^ swzr;
            short8 af[4], bf_[4];
            #pragma unroll
            for (int x = 0; x < 4; ++x)
                af[x] = *reinterpret_cast<const short8*>((char*)As + (wm + 16 * x + lq) * 128 + cb);
            #pragma unroll
            for (int y = 0; y < 4; ++y)
                bf_[y] = *reinterpret_cast<const short8*>((char*)Bs + (wn + 16 * y + lq) * 128 + cb);
            #pragma unroll
            for (int x = 0; x < 4; ++x)
                #pragma unroll
                for (int y = 0; y < 4; ++y)
                    acc[x][y] = __builtin_amdgcn_mfma_f32_16x16x32_bf16(af[x], bf_[y], acc[x][y], 0, 0, 0);
        }
    }
    const int nn = ((bn + wn) >> 6) & 15;   // head index (OUT==3)
    #pragma unroll
    for (int x = 0; x < 4; ++x) {
        #pragma unroll
        for (int y = 0; y < 4; ++y) {
            const int col = bn + wn + 16 * y + lq;
            #pragma unroll
            for (int r = 0; r < 4; ++r) {
                const int row = bm + wm + 16 * x + 4 * lg + r;
                float v = acc[x][y][r];
                if constexpr (BIAS) { if (z == 0) v += bias[col]; }
                if constexpr (RELU) v = fmaxf(v, 0.f);
                if constexpr (OUT == 0) Cf[zoff + (size_t)row * N + col] = v;
                else if constexpr (OUT == 1) Cb[zoff + (size_t)row * N + col] = f2bf(v);
                else  // OUT == 3: rhk head-major [n][row][d]
                    Cb[((size_t)nn * 1024 + row) * 64 + 16 * y + lq] = f2bf(v);
            }
        }
    }
}

// ---------------- deep-pipeline bf16 MFMA GEMM (round-6 form, proven): ff2 ---
template<bool BIAS, bool RELU, int OUT>
__global__ __launch_bounds__(512, 2) void gemm_deep(
    const u16* __restrict__ A, const u16* __restrict__ BT,
    const float* __restrict__ bias,
    float* __restrict__ Cf, u16* __restrict__ Cb,
    int M, int N, int K, int lda, int ldb)
{
    __shared__ u16 lds[3 * 24576];        // 3 x (A 256x64 + B 128x64) = 144 KB
    const int bm = blockIdx.y * 256, bn = blockIdx.x * 128;
    const int z = blockIdx.z;
    A  += (size_t)z * K;
    BT += (size_t)z * K;
    const size_t zoff = (size_t)z * M * N;
    const int t = threadIdx.x;            // 0..511
    const int w = t >> 6, l = t & 63, lg = l >> 4, lq = l & 15;
    const int wm = (w >> 1) * 64;
    const int wn = (w & 1) * 64;
    const int srow = t >> 3, slot = t & 7;
    const int gcol = (slot * 16) ^ ((srow & 7) << 4);
    const int swzr = (lq & 7) << 4;

    auto stage_tile = [&](int kt, int buf) {
        const int k0 = kt * 64;
        char* Ab = (char*)lds + buf * 49152 + w * 1024;
        char* Bb = (char*)lds + buf * 49152 + 32768 + w * 1024;
        #pragma unroll
        for (int i = 0; i < 4; ++i)
            gload16((const char*)A + (((size_t)(bm + i * 64 + srow) * lda + k0) << 1) + gcol,
                    Ab + i * 8192);
        #pragma unroll
        for (int i = 0; i < 2; ++i)
            gload16((const char*)BT + (((size_t)(bn + i * 64 + srow) * ldb + k0) << 1) + gcol,
                    Bb + i * 8192);
    };

    f32x4 acc[4][4];
    #pragma unroll
    for (int x = 0; x < 4; ++x)
        #pragma unroll
        for (int y = 0; y < 4; ++y)
            acc[x][y] = (f32x4){0.f, 0.f, 0.f, 0.f};

    const int NT = K >> 6;
    stage_tile(0, 0);
    stage_tile(1, 1);

    for (int kt = 0; kt < NT; ++kt) {
        if (kt < NT - 1) asm volatile("s_waitcnt vmcnt(6)" ::: "memory");
        else             asm volatile("s_waitcnt vmcnt(0)" ::: "memory");
        __builtin_amdgcn_s_barrier();
        __builtin_amdgcn_sched_barrier(0);
        if (kt + 2 < NT) stage_tile(kt + 2, (kt + 2) % 3);

        const char* Ab = (const char*)lds + (kt % 3) * 49152;
        const char* Bb = Ab + 32768;
        #pragma unroll
        for (int ks = 0; ks < 2; ++ks) {
            const int cb = (ks * 64 + 16 * lg) ^ swzr;
            short8 af[4], bf_[4];
            #pragma unroll
            for (int x = 0; x < 4; ++x)
                af[x] = *reinterpret_cast<const short8*>(Ab + (wm + 16 * x + lq) * 128 + cb);
            #pragma unroll
            for (int y = 0; y < 4; ++y)
                bf_[y] = *reinterpret_cast<const short8*>(Bb + (wn + 16 * y + lq) * 128 + cb);
            __builtin_amdgcn_s_setprio(1);
            #pragma unroll
            for (int x = 0; x < 4; ++x)
                #pragma unroll
                for (int y = 0; y < 4; ++y)
                    acc[x][y] = __builtin_amdgcn_mfma_f32_16x16x32_bf16(af[x], bf_[y], acc[x][y], 0, 0, 0);
            __builtin_amdgcn_s_setprio(0);
        }
    }

    #pragma unroll
    for (int x = 0; x < 4; ++x) {
        #pragma unroll
        for (int y = 0; y < 4; ++y) {
            const int col = bn + wn + 16 * y + lq;
            #pragma unroll
            for (int r = 0; r < 4; ++r) {
                const int row = bm + wm + 16 * x + 4 * lg + r;
                float v = acc[x][y][r];
                if constexpr (BIAS) { if (z == 0) v += bias[col]; }
                if constexpr (RELU) v = fmaxf(v, 0.f);
                if constexpr (OUT == 0) Cf[zoff + (size_t)row * N + col] = v;
                else Cb[zoff + (size_t)row * N + col] = f2bf(v);
            }
        }
    }
}

// ---------------- 256x256 counted-vmcnt + read-ahead GEMM (round-16) ---------
// Round-15 proven schedule + T1 chunked XCD swizzle: default dispatch round-
// robins consecutive blockIdx.x across the 8 XCDs, so the 4-8 blocks sharing
// an A-panel land on DIFFERENT XCD-L2s (A fetched ~8x from HBM; measured
// FETCH 80MB vs 23MB ideal). Remap id=(bid%8)*(nwg/8)+bid/8 (bijective since
// nwg%8==0) so each XCD owns a contiguous chunk containing whole bm-groups ->
// stage loads hit L2 (~200cy) instead of HBM (~900cy), shortening vmcnt waits.
// OUT: 1 = bf16 flat; 2 = QKV head-major with Q-skip (320-block grid).
template<bool BIAS, bool RELU, int OUT>
__global__ __launch_bounds__(512, 2) void gemm256(
    const u16* __restrict__ A, const u16* __restrict__ BT,
    const float* __restrict__ bias, u16* __restrict__ Cb,
    int N, int K, int lda, int ldb, int nbx)
{
    __shared__ u16 lds[2 * 32768];        // 2 x (A 256x64 + B 256x64) = 128 KB
    // T1 chunked XCD swizzle (gridDim.x % 8 == 0 for all users: 320, 256)
    const int id = ((int)blockIdx.x % 8) * ((int)gridDim.x / 8) + (int)blockIdx.x / 8;
    int bm, bn;
    if constexpr (OUT == 2) {             // QKV with Q-skip
        if (id < 64) { bm = 4096 + (id >> 2) * 256; bn = (id & 3) * 256; }
        else         { int j = id - 64; bm = (j >> 3) * 256; bn = 1024 + (j & 7) * 256; }
    } else {
        bm = (id / nbx) * 256; bn = (id % nbx) * 256;
    }
    const int t = threadIdx.x;            // 0..511
    const int w = t >> 6, l = t & 63, lg = l >> 4, lq = l & 15;
    const int wm = (w >> 2) * 128;        // 2 M-groups of 128
    const int wn = (w & 3) * 64;          // 4 N-groups of 64
    const int srow = t >> 3, slot = t & 7;
    const int gcol = (slot * 16) ^ ((srow & 7) << 4);
    const int swzr = (lq & 7) << 4;

    auto stage_unit = [&](int kt, char* buf, int u) {
        const int k0 = kt * 64;
        if (u < 2) {            // B row-groups {2u, 2u+1}
            #pragma unroll
            for (int i = 0; i < 2; ++i) {
                int g = u * 2 + i;
                gload16((const char*)BT + (((size_t)(bn + g * 64 + srow) * ldb + k0) << 1) + gcol,
                        buf + 32768 + g * 8192 + w * 1024);
            }
        } else {                // A row-groups {u-2, u}: u2={0,2} (mh0), u3={1,3} (mh1)
            #pragma unroll
            for (int i = 0; i < 2; ++i) {
                int g = (u - 2) + i * 2;
                gload16((const char*)A + (((size_t)(bm + g * 64 + srow) * lda + k0) << 1) + gcol,
                        buf + g * 8192 + w * 1024);
            }
        }
    };

    f32x4 acc[8][4];
    #pragma unroll
    for (int m = 0; m < 8; ++m)
        #pragma unroll
        for (int y = 0; y < 4; ++y)
            acc[m][y] = (f32x4){0.f, 0.f, 0.f, 0.f};

    const int NT = K >> 6;
    #pragma unroll
    for (int u = 0; u < 4; ++u) stage_unit(0, (char*)lds, u);

    for (int kt = 0; kt < NT; ++kt) {
        const char* Ab = (const char*)lds + (kt & 1) * 65536;
        const char* Bb = Ab + 32768;
        char* nbuf = (char*)lds + ((kt + 1) & 1) * 65536;
        const bool pf = (kt + 1 < NT);
        const int cb0 = (16 * lg) ^ swzr;
        const int cb1 = (64 + 16 * lg) ^ swzr;

        short8 bk0[4], bk1[4], a00[4], a01[4], a10[4], a11[4];

        // ---- phase 0: (mh0, ks0); reads touch only u0-u2
        asm volatile("s_waitcnt vmcnt(2)" ::: "memory");
        __builtin_amdgcn_s_barrier();
        __builtin_amdgcn_sched_barrier(0);
        #pragma unroll
        for (int y = 0; y < 4; ++y)
            bk0[y] = *reinterpret_cast<const short8*>(Bb + (wn + 16 * y + lq) * 128 + cb0);
        __builtin_amdgcn_sched_barrier(0);
        #pragma unroll
        for (int x = 0; x < 4; ++x)
            a00[x] = *reinterpret_cast<const short8*>(Ab + (wm + 16 * x + lq) * 128 + cb0);
        __builtin_amdgcn_sched_barrier(0);
        #pragma unroll
        for (int y = 0; y < 4; ++y)
            bk1[y] = *reinterpret_cast<const short8*>(Bb + (wn + 16 * y + lq) * 128 + cb1);
        __builtin_amdgcn_sched_barrier(0);
        #pragma unroll
        for (int x = 0; x < 4; ++x)
            a01[x] = *reinterpret_cast<const short8*>(Ab + (wm + 16 * x + lq) * 128 + cb1);
        __builtin_amdgcn_sched_barrier(0);
        if (pf) stage_unit(kt + 1, nbuf, 0);
        asm volatile("s_waitcnt lgkmcnt(8)" ::: "memory");
        __builtin_amdgcn_sched_barrier(0);
        __builtin_amdgcn_s_setprio(1);
        #pragma unroll
        for (int x = 0; x < 4; ++x)
            #pragma unroll
            for (int y = 0; y < 4; ++y)
                acc[x][y] = __builtin_amdgcn_mfma_f32_16x16x32_bf16(a00[x], bk0[y], acc[x][y], 0, 0, 0);
        __builtin_amdgcn_s_setprio(0);

        // ---- phase 1: (mh0, ks1); u3 now resident after this vmcnt
        if (pf) asm volatile("s_waitcnt vmcnt(2)" ::: "memory");
        else    asm volatile("s_waitcnt vmcnt(0)" ::: "memory");
        __builtin_amdgcn_s_barrier();
        __builtin_amdgcn_sched_barrier(0);
        #pragma unroll
        for (int x = 0; x < 4; ++x)
            a10[x] = *reinterpret_cast<const short8*>(Ab + (wm + 64 + 16 * x + lq) * 128 + cb0);
        __builtin_amdgcn_sched_barrier(0);
        #pragma unroll
        for (int x = 0; x < 4; ++x)
            a11[x] = *reinterpret_cast<const short8*>(Ab + (wm + 64 + 16 * x + lq) * 128 + cb1);
        __builtin_amdgcn_sched_barrier(0);
        if (pf) stage_unit(kt + 1, nbuf, 1);
        asm volatile("s_waitcnt lgkmcnt(8)" ::: "memory");
        __builtin_amdgcn_sched_barrier(0);
        __builtin_amdgcn_s_setprio(1);
        #pragma unroll
        for (int x = 0; x < 4; ++x)
            #pragma unroll
            for (int y = 0; y < 4; ++y)
                acc[x][y] = __builtin_amdgcn_mfma_f32_16x16x32_bf16(a01[x], bk1[y], acc[x][y], 0, 0, 0);
        __builtin_amdgcn_s_setprio(0);

        // ---- phase 2: (mh1, ks0)
        __builtin_amdgcn_s_barrier();
        __builtin_amdgcn_sched_barrier(0);
        if (pf) stage_unit(kt + 1, nbuf, 2);
        asm volatile("s_waitcnt lgkmcnt(4)" ::: "memory");
        __builtin_amdgcn_sched_barrier(0);
        __builtin_amdgcn_s_setprio(1);
        #pragma unroll
        for (int x = 0; x < 4; ++x)
            #pragma unroll
            for (int y = 0; y < 4; ++y)
                acc[4 + x][y] = __builtin_amdgcn_mfma_f32_16x16x32_bf16(a10[x], bk0[y], acc[4 + x][y], 0, 0, 0);
        __builtin_amdgcn_s_setprio(0);

        // ---- phase 3: (mh1, ks1)
        __builtin_amdgcn_s_barrier();
        __builtin_amdgcn_sched_barrier(0);
        if (pf) stage_unit(kt + 1, nbuf, 3);
        asm volatile("s_waitcnt lgkmcnt(0)" ::: "memory");
        __builtin_amdgcn_sched_barrier(0);
        __builtin_amdgcn_s_setprio(1);
        #pragma unroll
        for (int x = 0; x < 4; ++x)
            #pragma unroll
            for (int y = 0; y < 4; ++y)
                acc[4 + x][y] = __builtin_amdgcn_mfma_f32_16x16x32_bf16(a11[x], bk1[y], acc[4 + x][y], 0, 0, 0);
        __builtin_amdgcn_s_setprio(0);
    }

    #pragma unroll
    for (int m = 0; m < 8; ++m) {
        #pragma unroll
        for (int y = 0; y < 4; ++y) {
            const int col = bn + wn + 16 * y + lq;
            #pragma unroll
            for (int r = 0; r < 4; ++r) {
                const int row = bm + wm + m * 16 + 4 * lg + r;
                float v = acc[m][y][r];
                if constexpr (BIAS) v += bias[col];
                if constexpr (RELU) v = fmaxf(v, 0.f);
                if constexpr (OUT == 2) {   // head-major: row = key*8+b
                    const int part = col >> 10, nn = (col >> 6) & 15;
                    Cb[(size_t)part * HM_PART
                       + ((size_t)((row & 7) * 16 + nn) * 1024 + (row >> 3)) * 64
                       + (col & 63)] = f2bf(v);
                } else {
                    Cb[(size_t)row * N + col] = f2bf(v);
                }
            }
        }
    }
}

// ---------------- MFMA flash relative attention (round-13 form, proven) ------
__global__ __launch_bounds__(512, 4) void attn_mfma(
    const u16* __restrict__ Hm,      // head-major Q|K|V, parts of [(b,h)][tok][d]
    const u16* __restrict__ Vg,      // bf16 [(b,h)][DH][KLEN]
    const u16* __restrict__ rhm,     // bf16 head-major [h][o][d]
    const float* __restrict__ rwb, const float* __restrict__ rrb,
    u16* __restrict__ vec)           // bf16 [QLEN*BSZ][NH*DH]
{
    const int bnidx = blockIdx.x;                // b*16+n
    const int b = bnidx >> 4;
    const int n = bnidx & 15;
    const int i0 = (3 - blockIdx.y) * 128;       // long blocks first
    const int t = threadIdx.x;
    const int w = t >> 6;                        // 0..7
    const int l = t & 63;
    const int lg = l >> 4, lq = l & 15;
    const int r8 = l >> 3, sl = l & 7;

    const u16* Qh = Hm;
    const u16* Kh = Hm + HM_PART;

    __shared__ u16 Ks[64 * 64];
    __shared__ u16 Vt[64 * 64];
    __shared__ u16 Rs[192 * 64];
    __shared__ u16 SbO[8 * 16 * 84];
    __shared__ u16 Ps[8 * 16 * 64];

    u16* SbW = SbO + w * 16 * 84;
    u16* PsW = Ps + w * 16 * 64;
    const int swzr = (lq & 7) << 4;
    const int stg_swz = (sl * 16) ^ (r8 << 4);
    const int lofs = l * 16;
    const int rbase = 384 - i0;
    const int ntiles = i0 / 64 + 10;

    auto kSrc = [&](int tile) {
        return (const char*)Kh + (((size_t)bnidx * 1024 + (tile << 6) + w * 8 + r8) * 64 << 1) + stg_swz;
    };
    auto vSrc = [&](int tile) {
        return (const char*)Vg + ((((size_t)bnidx * 64 + w * 8 + r8) * KLEN + (tile << 6)) << 1) + stg_swz;
    };
    auto rSrc = [&](int g) {
        int o = rbase + g * 64 + w * 8 + r8;
        o = o > (KLEN - 1) ? (KLEN - 1) : o;
        return (const char*)rhm + (((size_t)n * 1024 + o) * 64 << 1) + stg_swz;
    };

    // Q fragments with 1/sqrt(d)=0.125 folded in
    short8 qw[2], qr[2];
    {
        const size_t qbase = ((size_t)bnidx * 1024 + MLEN + i0 + 16 * w + lq) * 64;
        #pragma unroll
        for (int ks = 0; ks < 2; ++ks) {
            short8 qv = *reinterpret_cast<const short8*>(&Qh[qbase + ks * 32 + 8 * lg]);
            short8 xw, xr;
            #pragma unroll
            for (int e = 0; e < 8; ++e) {
                float f = bf2f((u16)qv[e]);
                int d = ks * 32 + 8 * lg + e;
                xw[e] = (short)f2bf((f + rwb[n * 64 + d]) * 0.125f);
                xr[e] = (short)f2bf((f + rrb[n * 64 + d]) * 0.125f);
            }
            qw[ks] = xw; qr[ks] = xr;
        }
    }

    float m_run = NEGF, l_run = 0.f;
    f32x4 acc[4];
    #pragma unroll
    for (int df = 0; df < 4; ++df) acc[df] = (f32x4){0.f, 0.f, 0.f, 0.f};

    const int s0 = 112 - 16 * w;

    // prologue: tile-0 staging into registers
    u32x4 kreg = *reinterpret_cast<const u32x4*>(kSrc(0));
    u32x4 vreg = *reinterpret_cast<const u32x4*>(vSrc(0));
    u32x4 rr0  = *reinterpret_cast<const u32x4*>(rSrc(0));
    u32x4 rr1  = *reinterpret_cast<const u32x4*>(rSrc(1));
    u32x4 rr2  = *reinterpret_cast<const u32x4*>(rSrc(2));

    for (int tile = 0; tile < ntiles; ++tile) {
        const int j0 = tile << 6;
        __builtin_amdgcn_s_barrier();            // all waves done reading prev tile
        __builtin_amdgcn_sched_barrier(0);
        *reinterpret_cast<u32x4*>((char*)Ks + w * 1024 + lofs) = kreg;
        *reinterpret_cast<u32x4*>((char*)Vt + w * 1024 + lofs) = vreg;
        if (tile == 0) {
            *reinterpret_cast<u32x4*>((char*)Rs + 0 * 8192 + w * 1024 + lofs) = rr0;
            *reinterpret_cast<u32x4*>((char*)Rs + 1 * 8192 + w * 1024 + lofs) = rr1;
            *reinterpret_cast<u32x4*>((char*)Rs + 2 * 8192 + w * 1024 + lofs) = rr2;
        } else {
            *reinterpret_cast<u32x4*>((char*)Rs + ((tile + 2) % 3) * 8192 + w * 1024 + lofs) = rr0;
        }
        if (tile + 1 < ntiles) {
            kreg = *reinterpret_cast<const u32x4*>(kSrc(tile + 1));
            vreg = *reinterpret_cast<const u32x4*>(vSrc(tile + 1));
            rr0  = *reinterpret_cast<const u32x4*>(rSrc(tile + 3));
        }
        asm volatile("s_waitcnt lgkmcnt(0)" ::: "memory");
        __builtin_amdgcn_s_barrier();            // all waves' ds_writes visible
        __builtin_amdgcn_sched_barrier(0);

        const int bmax = i0 + 16 * w + 15 + MLEN - j0;
        if (bmax < 0) continue;                  // per-wave skip; barriers balanced

        __builtin_amdgcn_s_setprio(1);
        #pragma unroll
        for (int ff = 0; ff < 5; ++ff) {
            const int olf = s0 + 16 * ff;
            const int srowb = ((tile + (olf >> 6)) % 3) * 64 + (olf & 63);
            f32x4 d = (f32x4){0.f, 0.f, 0.f, 0.f};
            #pragma unroll
            for (int ks = 0; ks < 2; ++ks) {
                short8 a = *reinterpret_cast<const short8*>(
                    (char*)Rs + (srowb + lq) * 128 + ((ks * 64 + 16 * lg) ^ swzr));
                d = __builtin_amdgcn_mfma_f32_16x16x32_bf16(a, qr[ks], d, 0, 0, 0);
            }
            s16x4 pk;
            #pragma unroll
            for (int r = 0; r < 4; ++r) pk[r] = (short)f2bf(d[r]);
            *reinterpret_cast<s16x4*>(&SbW[lq * 84 + 16 * ff + 4 * lg]) = pk;
        }
        f32x4 dac[4];
        #pragma unroll
        for (int f = 0; f < 4; ++f) {
            f32x4 d = (f32x4){0.f, 0.f, 0.f, 0.f};
            #pragma unroll
            for (int ks = 0; ks < 2; ++ks) {
                short8 a = *reinterpret_cast<const short8*>(
                    (char*)Ks + (16 * f + lq) * 128 + ((ks * 64 + 16 * lg) ^ swzr));
                d = __builtin_amdgcn_mfma_f32_16x16x32_bf16(a, qw[ks], d, 0, 0, 0);
            }
            dac[f] = d;
        }
        __builtin_amdgcn_s_setprio(0);

        const bool fullTile = (i0 + 16 * w + MLEN - j0) >= 63;
        float sv[4][4];
        float mx = NEGF;
        if (fullTile) {
            #pragma unroll
            for (int f = 0; f < 4; ++f)
                #pragma unroll
                for (int r = 0; r < 4; ++r) {
                    int k = 16 * f + 4 * lg + r;
                    float x = dac[f][r] + bf2f(SbW[lq * 84 + k - lq + 15]);
                    sv[f][r] = x;
                    mx = fmaxf(mx, x);
                }
        } else {
            const int bound = i0 + 16 * w + lq + MLEN - j0;
            #pragma unroll
            for (int f = 0; f < 4; ++f)
                #pragma unroll
                for (int r = 0; r < 4; ++r) {
                    int k = 16 * f + 4 * lg + r;
                    float x = (k <= bound)
                        ? dac[f][r] + bf2f(SbW[lq * 84 + k - lq + 15]) : NEGF;
                    sv[f][r] = x;
                    mx = fmaxf(mx, x);
                }
        }
        mx = fmaxf(mx, __shfl_xor(mx, 16));
        mx = fmaxf(mx, __shfl_xor(mx, 32));
        const bool defer = (__all(mx <= m_run + 8.0f) != 0);
        const float m_new = defer ? m_run : fmaxf(m_run, mx);
        float ps = 0.f;
        #pragma unroll
        for (int f = 0; f < 4; ++f) {
            s16x4 pk;
            #pragma unroll
            for (int r = 0; r < 4; ++r) {
                float p = __expf(sv[f][r] - m_new);
                ps += p;
                pk[r] = (short)f2bf(p);
            }
            *reinterpret_cast<s16x4*>(
                (char*)PsW + lq * 128 + (((4 * f + lg) ^ ((lq & 7) << 1)) << 3)) = pk;
        }
        ps += __shfl_xor(ps, 16);
        ps += __shfl_xor(ps, 32);
        if (defer) {
            l_run += ps;
        } else {
            float alpha = __expf(m_run - m_new);
            l_run = l_run * alpha + ps;
            m_run = m_new;
            float alr[4];
            #pragma unroll
            for (int r = 0; r < 4; ++r) alr[r] = __shfl(alpha, 20 * lg + r);
            #pragma unroll
            for (int df = 0; df < 4; ++df)
                #pragma unroll
                for (int r = 0; r < 4; ++r) acc[df][r] *= alr[r];
        }

        __builtin_amdgcn_s_setprio(1);
        #pragma unroll
        for (int df = 0; df < 4; ++df) {
            f32x4 a = acc[df];
            #pragma unroll
            for (int ks = 0; ks < 2; ++ks) {
                short8 pa = *reinterpret_cast<const short8*>(
                    (char*)PsW + lq * 128 + ((ks * 64 + 16 * lg) ^ swzr));
                short8 vb = *reinterpret_cast<const short8*>(
                    (char*)Vt + (16 * df + lq) * 128 + ((ks * 64 + 16 * lg) ^ swzr));
                a = __builtin_amdgcn_mfma_f32_16x16x32_bf16(pa, vb, a, 0, 0, 0);
            }
            acc[df] = a;
        }
        __builtin_amdgcn_s_setprio(0);
    }

    float inv[4];
    #pragma unroll
    for (int r = 0; r < 4; ++r) inv[r] = 1.f / __shfl(l_run, 20 * lg + r);
    #pragma unroll
    for (int df = 0; df < 4; ++df) {
        #pragma unroll
        for (int r = 0; r < 4; ++r) {
            const int il = 16 * w + 4 * lg + r;
            float o = acc[df][r] * inv[r];
            vec[((size_t)((i0 + il) * BSZ + b)) * DM + n * 64 + 16 * df + lq] = f2bf(o);
        }
    }
}

// ---------------- Residual + LayerNorm (1 or 2 extra fp32 residual streams) --
template<int NRES, bool WB>
__global__ __launch_bounds__(256) void ln_res_kernel(
    const float* __restrict__ x, const float* __restrict__ res,
    const float* __restrict__ res2,
    const float* __restrict__ g, const float* __restrict__ bta,
    float* __restrict__ out, u16* __restrict__ outb)
{
    const int row = blockIdx.x;
    const int t = threadIdx.x;
    const int lane = t & 63, wv = t >> 6;
    __shared__ float red0[4], red1[4];

    float4 a = ldg4(&x[(size_t)row * DM + t * 4]);
    float4 b = ldg4(&res[(size_t)row * DM + t * 4]);
    float v0 = a.x + b.x, v1 = a.y + b.y, v2 = a.z + b.z, v3 = a.w + b.w;
    if constexpr (NRES == 2) {
        float4 c = ldg4(&res2[(size_t)row * DM + t * 4]);
        v0 += c.x; v1 += c.y; v2 += c.z; v3 += c.w;
    }
    float s = v0 + v1 + v2 + v3;
    #pragma unroll
    for (int o = 32; o; o >>= 1) s += __shfl_xor(s, o);
    if (lane == 0) red0[wv] = s;
    __syncthreads();
    float mu = (red0[0] + red0[1] + red0[2] + red0[3]) * (1.f / DM);
    float d0 = v0 - mu, d1 = v1 - mu, d2 = v2 - mu, d3 = v3 - mu;
    float q = d0*d0 + d1*d1 + d2*d2 + d3*d3;
    #pragma unroll
    for (int o = 32; o; o >>= 1) q += __shfl_xor(q, o);
    if (lane == 0) red1[wv] = q;
    __syncthreads();
    float var = (red1[0] + red1[1] + red1[2] + red1[3]) * (1.f / DM);
    float rs = rsqrtf(var + 1e-5f);
    float4 gv = ldg4(&g[t * 4]);
    float4 bv = ldg4(&bta[t * 4]);
    float o0 = d0 * rs * gv.x + bv.x;
    float o1 = d1 * rs * gv.y + bv.y;
    float o2 = d2 * rs * gv.z + bv.z;
    float o3 = d3 * rs * gv.w + bv.w;
    float4 o4 = make_float4(o0, o1, o2, o3);
    *reinterpret_cast<float4*>(&out[(size_t)row * DM + t * 4]) = o4;
    if constexpr (WB) {
        u16 ob[4] = { f2bf(o0), f2bf(o1), f2bf(o2), f2bf(o3) };
        *reinterpret_cast<uint2*>(&outb[(size_t)row * DM + t * 4]) = *reinterpret_cast<uint2*>(ob);
    }
}

// ---------------- launch ------------------------------------------------------
extern "C" void kernel_launch(void* const* d_in, const int* in_sizes, int n_in,
                              void* d_out, int out_size, void* d_ws, size_t ws_size,
                              hipStream_t stream) {
    const float* w     = (const float*)d_in[0];
    const float* r     = (const float*)d_in[1];
    const float* mems  = (const float*)d_in[2];
    const float* w_qkv = (const float*)d_in[3];
    const float* w_r   = (const float*)d_in[4];
    const float* w_o   = (const float*)d_in[5];
    const float* rwb   = (const float*)d_in[6];
    const float* rrb   = (const float*)d_in[7];
    const float* ln1g  = (const float*)d_in[8];
    const float* ln1b  = (const float*)d_in[9];
    const float* ffw1  = (const float*)d_in[10];
    const float* ffb1  = (const float*)d_in[11];
    const float* ffw2  = (const float*)d_in[12];
    const float* ffb2  = (const float*)d_in[13];
    const float* ln2g  = (const float*)d_in[14];
    const float* ln2b  = (const float*)d_in[15];
    (void)in_sizes; (void)n_in; (void)out_size; (void)ws_size;

    char* p = (char*)d_ws;
    auto alloc = [&](size_t bytes) { char* q = p; p += (bytes + 255) & ~(size_t)255; return q; };
    u16* catB   = (u16*)alloc((size_t)8192 * 1024 * 2);   // reused as Vg after QKV GEMM
    u16* rB     = (u16*)alloc((size_t)1024 * 1024 * 2);
    u16* qkvT   = (u16*)alloc((size_t)3072 * 1024 * 2);
    u16* wrT    = (u16*)alloc((size_t)1024 * 1024 * 2);
    u16* woT    = (u16*)alloc((size_t)1024 * 1024 * 2);
    u16* f1T    = (u16*)alloc((size_t)4096 * 1024 * 2);
    u16* f2T    = (u16*)alloc((size_t)1024 * 4096 * 2);
    u16* headsHm= (u16*)alloc((size_t)3 * HM_PART * 2);   // reused as ff2[2] after attn
    u16* rhkHm  = (u16*)alloc((size_t)1024 * 1024 * 2);
    u16* vec    = (u16*)alloc((size_t)4096 * 1024 * 2);
    u16* hB     = (u16*)alloc((size_t)4096 * 1024 * 2);
    u16* ff1    = (u16*)alloc((size_t)4096 * 4096 * 2);   // doubles as attn_out[2] before ff1
    float* hF   = (float*)alloc((size_t)4096 * 1024 * 4);

    u16* Vg = catB;
    float* attn_out = (float*)ff1;
    float* ff2 = (float*)headsHm;
    float* outp = (float*)d_out;

    // fused casts + fused weight transposes
    cast_all<<<9216, 256, 0, stream>>>(mems, w, r, catB, rB);
    transpose_all<<<13312, 256, 0, stream>>>(w_qkv, qkvT, w_r, wrT, w_o, woT,
                                             ffw1, f1T, ffw2, f2T);

    // 1. heads = cat @ w_qkv -> head-major Q|K|V, Q computed only for tok>=512
    gemm256<false, false, 2><<<320, 512, 0, stream>>>(
        catB, qkvT, nullptr, headsHm, 3072, 1024, 1024, 1024, 0);
    // 2. V transpose (catB dead -> Vg aliases it); reads V_hm part
    v_transpose<<<dim3(128, 16), 256, 0, stream>>>(headsHm + 2 * HM_PART, Vg);
    // 3. rhk = r @ w_r -> head-major [h][o][d]
    gemm_mfma<false, false, 3><<<dim3(8, 8), 256, 0, stream>>>(
        rB, wrT, nullptr, nullptr, rhkHm, 1024, 1024, 1024, 1024, 1024);
    // 4. attention (T14 reg-staged prefetch)
    attn_mfma<<<dim3(BSZ * NH, QLEN / 128), 512, 0, stream>>>(
        headsHm, Vg, rhkHm, rwb, rrb, vec);
    // 5. attn_out = vec @ w_o, split-K x2 (128^2 kernel, fp32 partials)
    gemm_mfma<false, false, 0><<<dim3(8, 32, 2), 256, 0, stream>>>(
        vec, woT, nullptr, attn_out, nullptr, 4096, 1024, 512, 1024, 1024);
    // 6. h = LN(w + ao0 + ao1), keep fp32 + bf16
    ln_res_kernel<2, true><<<4096, 256, 0, stream>>>(
        w, attn_out, attn_out + (size_t)4096 * 1024, ln1g, ln1b, hF, hB);
    // 7. ff1 = relu(h @ ff_w1 + b1)  (read-ahead 256^2 + XCD swizzle)
    gemm256<true, true, 1><<<256, 512, 0, stream>>>(
        hB, f1T, ffb1, ff1, 4096, 1024, 1024, 1024, 16);
    // 8. ff2 = ff1 @ ff_w2 + b2, split-K x2 (proven deep kernel, fp32 partials)
    gemm_deep<true, false, 0><<<dim3(8, 16, 2), 512, 0, stream>>>(
        ff1, f2T, ffb2, ff2, nullptr, 4096, 1024, 2048, 4096, 4096);
    // 9. out = LN(h + ff2a + ff2b)
    ln_res_kernel<2, false><<<4096, 256, 0, stream>>>(
        hF, ff2, ff2 + (size_t)4096 * 1024, ln2g, ln2b, outp, nullptr);
}

// Round 17
// 282.184 us; speedup vs baseline: 1.0711x; 1.0623x over previous
//
#include <hip/hip_runtime.h>
#include <hip/hip_bf16.h>

#define QLEN 512
#define MLEN 512
#define KLEN 1024
#define BSZ 8
#define DM 1024
#define NH 16
#define DH 64
#define DI 4096
#define NEGF (-1e30f)
#define HM_PART ((size_t)8388608)   // 128*1024*64 u16 per Q/K/V part

typedef unsigned short u16;
typedef __attribute__((ext_vector_type(8))) short short8;
typedef __attribute__((ext_vector_type(4))) short s16x4;
typedef __attribute__((ext_vector_type(4))) float f32x4;
typedef __attribute__((ext_vector_type(4))) unsigned int u32x4;

__device__ __forceinline__ float bf2f(u16 u) {
    union { unsigned i; float f; } x; x.i = ((unsigned)u) << 16; return x.f;
}
__device__ __forceinline__ u16 f2bf(float f) {
    __hip_bfloat16 h = __float2bfloat16(f);
    return *reinterpret_cast<u16*>(&h);
}
__device__ __forceinline__ float4 ldg4(const float* p) {
    return *reinterpret_cast<const float4*>(p);
}
// async global->LDS DMA, 16B per lane; LDS dest = wave-uniform base (+ lane*16 by HW)
__device__ __forceinline__ void gload16(const void* g, void* l) {
    __builtin_amdgcn_global_load_lds(
        (const __attribute__((address_space(1))) void*)g,
        (__attribute__((address_space(3))) void*)l, 16, 0, 0);
}

// ---------------- fused casts: mems|w -> catB, r -> rB -----------------------
__global__ __launch_bounds__(256) void cast_all(
    const float* __restrict__ mems, const float* __restrict__ w,
    const float* __restrict__ r, u16* __restrict__ catB, u16* __restrict__ rB)
{
    int idx = (blockIdx.x * 256 + threadIdx.x) * 4;
    const float* src;
    u16* dst;
    if (idx < 8388608) {   // catB: mems (first 4M elems) then w
        src = (idx < 4194304) ? (mems + idx) : (w + idx - 4194304);
        dst = catB + idx;
    } else {
        int i2 = idx - 8388608;
        if (i2 >= 1048576) return;
        src = r + i2;
        dst = rB + i2;
    }
    float4 v = ldg4(src);
    u16 o[4] = { f2bf(v.x), f2bf(v.y), f2bf(v.z), f2bf(v.w) };
    *reinterpret_cast<uint2*>(dst) = *reinterpret_cast<uint2*>(o);
}

// ---------------- fused weight transposes: 5 matrices in one launch ----------
__device__ __forceinline__ void tr32(
    const float* __restrict__ W, u16* __restrict__ WT, int K, int N, int k0, int n0)
{
    __shared__ float tile[32][33];
    const int tx = threadIdx.x & 31, ty = threadIdx.x >> 5;
    #pragma unroll
    for (int j = 0; j < 4; ++j)
        tile[ty + j * 8][tx] = W[(size_t)(k0 + ty + j * 8) * N + n0 + tx];
    __syncthreads();
    #pragma unroll
    for (int j = 0; j < 4; ++j)
        WT[(size_t)(n0 + ty + j * 8) * K + k0 + tx] = f2bf(tile[tx][ty + j * 8]);
}

__global__ __launch_bounds__(256) void transpose_all(
    const float* __restrict__ w_qkv, u16* __restrict__ qkvT,
    const float* __restrict__ w_r,   u16* __restrict__ wrT,
    const float* __restrict__ w_o,   u16* __restrict__ woT,
    const float* __restrict__ ffw1,  u16* __restrict__ f1T,
    const float* __restrict__ ffw2,  u16* __restrict__ f2T)
{
    int id = blockIdx.x;
    if (id < 3072)       { int l = id;        tr32(w_qkv, qkvT, 1024, 3072, (l / 96) * 32, (l % 96) * 32); }
    else if (id < 4096)  { int l = id - 3072; tr32(w_r,   wrT,  1024, 1024, (l / 32) * 32, (l % 32) * 32); }
    else if (id < 5120)  { int l = id - 4096; tr32(w_o,   woT,  1024, 1024, (l / 32) * 32, (l % 32) * 32); }
    else if (id < 9216)  { int l = id - 5120; tr32(ffw1,  f1T,  1024, 4096, (l / 128) * 32, (l % 128) * 32); }
    else                 { int l = id - 9216; tr32(ffw2,  f2T,  4096, 1024, (l / 32) * 32, (l % 32) * 32); }
}

// ---------------- V transpose: V_hm[(b,h)][key][d] -> Vg[(b,h)][d][key] ------
__global__ __launch_bounds__(256) void v_transpose(
    const u16* __restrict__ Vhm, u16* __restrict__ Vg)
{
    const int bn = blockIdx.x;            // b*16+n
    const int kt = blockIdx.y;            // 64-key tile
    const int t = threadIdx.x;
    __shared__ u16 L[64 * 64];            // [key][d], col-swizzled

    #pragma unroll
    for (int rep = 0; rep < 2; ++rep) {
        int idx = t + rep * 256;
        int key = idx >> 3, dc = (idx & 7) * 8;
        short8 v = *reinterpret_cast<const short8*>(
            &Vhm[((size_t)bn * 1024 + kt * 64 + key) * 64 + dc]);
        *reinterpret_cast<short8*>((char*)L + key * 128 + ((dc * 2) ^ ((key & 7) << 4))) = v;
    }
    __syncthreads();
    #pragma unroll
    for (int rep = 0; rep < 2; ++rep) {
        int idx = t + rep * 256;
        int d = idx >> 3, kc = (idx & 7) * 8;
        short8 o;
        #pragma unroll
        for (int e = 0; e < 8; ++e)
            o[e] = *(const short*)((char*)L + (kc + e) * 128 + ((d * 2) ^ (((kc + e) & 7) << 4)));
        *reinterpret_cast<short8*>(&Vg[((size_t)(bn * 64 + d)) * KLEN + kt * 64 + kc]) = o;
    }
}

// ---------------- bf16 MFMA GEMM (m97 structure, 128x128): w_o ---------------
// OUT: 0 = fp32 flat, 1 = bf16 flat (zoff partials)
template<bool BIAS, bool RELU, int OUT>
__global__ __launch_bounds__(256) void gemm_mfma(
    const u16* __restrict__ A, const u16* __restrict__ BT,
    const float* __restrict__ bias,
    float* __restrict__ Cf, u16* __restrict__ Cb,
    int M, int N, int K, int lda, int ldb)
{
    __shared__ u16 As[128 * 64];
    __shared__ u16 Bs[128 * 64];
    const int bm = blockIdx.y * 128, bn = blockIdx.x * 128;
    const int z = blockIdx.z;
    A  += (size_t)z * K;
    BT += (size_t)z * K;
    const size_t zoff = (size_t)z * M * N;
    const int t = threadIdx.x;
    const int w = t >> 6, l = t & 63, lg = l >> 4, lq = l & 15;
    const int wm = (w >> 1) * 64, wn = (w & 1) * 64;
    const int r8 = l >> 3, slot = l & 7;
    const int gcol = (slot * 16) ^ (r8 << 4);

    f32x4 acc[4][4];
    #pragma unroll
    for (int x = 0; x < 4; ++x)
        #pragma unroll
        for (int y = 0; y < 4; ++y)
            acc[x][y] = (f32x4){0.f, 0.f, 0.f, 0.f};

    const int swzr = (lq & 7) << 4;

    for (int k0 = 0; k0 < K; k0 += 64) {
        __syncthreads();
        #pragma unroll
        for (int it = 0; it < 4; ++it) {
            const int base_row = w * 8 + it * 32;
            gload16((const char*)A + (((size_t)(bm + base_row + r8) * lda + k0) << 1) + gcol,
                    (char*)As + base_row * 128);
            gload16((const char*)BT + (((size_t)(bn + base_row + r8) * ldb + k0) << 1) + gcol,
                    (char*)Bs + base_row * 128);
        }
        __syncthreads();
        #pragma unroll
        for (int ks = 0; ks < 2; ++ks) {
            const int cb = (ks * 64 + 16 * lg) ^ swzr;
            short8 af[4], bf_[4];
            #pragma unroll
            for (int x = 0; x < 4; ++x)
                af[x] = *reinterpret_cast<const short8*>((char*)As + (wm + 16 * x + lq) * 128 + cb);
            #pragma unroll
            for (int y = 0; y < 4; ++y)
                bf_[y] = *reinterpret_cast<const short8*>((char*)Bs + (wn + 16 * y + lq) * 128 + cb);
            #pragma unroll
            for (int x = 0; x < 4; ++x)
                #pragma unroll
                for (int y = 0; y < 4; ++y)
                    acc[x][y] = __builtin_amdgcn_mfma_f32_16x16x32_bf16(af[x], bf_[y], acc[x][y], 0, 0, 0);
        }
    }
    #pragma unroll
    for (int x = 0; x < 4; ++x) {
        #pragma unroll
        for (int y = 0; y < 4; ++y) {
            const int col = bn + wn + 16 * y + lq;
            #pragma unroll
            for (int r = 0; r < 4; ++r) {
                const int row = bm + wm + 16 * x + 4 * lg + r;
                float v = acc[x][y][r];
                if constexpr (BIAS) { if (z == 0) v += bias[col]; }
                if constexpr (RELU) v = fmaxf(v, 0.f);
                if constexpr (OUT == 0) Cf[zoff + (size_t)row * N + col] = v;
                else Cb[zoff + (size_t)row * N + col] = f2bf(v);
            }
        }
    }
}

// ---------------- deep-pipeline bf16 MFMA GEMM (round-6 form, proven): ff2 ---
// OUT: 0 = fp32 partials, 1 = bf16 partials
template<bool BIAS, bool RELU, int OUT>
__global__ __launch_bounds__(512, 2) void gemm_deep(
    const u16* __restrict__ A, const u16* __restrict__ BT,
    const float* __restrict__ bias,
    float* __restrict__ Cf, u16* __restrict__ Cb,
    int M, int N, int K, int lda, int ldb)
{
    __shared__ u16 lds[3 * 24576];        // 3 x (A 256x64 + B 128x64) = 144 KB
    const int bm = blockIdx.y * 256, bn = blockIdx.x * 128;
    const int z = blockIdx.z;
    A  += (size_t)z * K;
    BT += (size_t)z * K;
    const size_t zoff = (size_t)z * M * N;
    const int t = threadIdx.x;            // 0..511
    const int w = t >> 6, l = t & 63, lg = l >> 4, lq = l & 15;
    const int wm = (w >> 1) * 64;
    const int wn = (w & 1) * 64;
    const int srow = t >> 3, slot = t & 7;
    const int gcol = (slot * 16) ^ ((srow & 7) << 4);
    const int swzr = (lq & 7) << 4;

    auto stage_tile = [&](int kt, int buf) {
        const int k0 = kt * 64;
        char* Ab = (char*)lds + buf * 49152 + w * 1024;
        char* Bb = (char*)lds + buf * 49152 + 32768 + w * 1024;
        #pragma unroll
        for (int i = 0; i < 4; ++i)
            gload16((const char*)A + (((size_t)(bm + i * 64 + srow) * lda + k0) << 1) + gcol,
                    Ab + i * 8192);
        #pragma unroll
        for (int i = 0; i < 2; ++i)
            gload16((const char*)BT + (((size_t)(bn + i * 64 + srow) * ldb + k0) << 1) + gcol,
                    Bb + i * 8192);
    };

    f32x4 acc[4][4];
    #pragma unroll
    for (int x = 0; x < 4; ++x)
        #pragma unroll
        for (int y = 0; y < 4; ++y)
            acc[x][y] = (f32x4){0.f, 0.f, 0.f, 0.f};

    const int NT = K >> 6;
    stage_tile(0, 0);
    stage_tile(1, 1);

    for (int kt = 0; kt < NT; ++kt) {
        if (kt < NT - 1) asm volatile("s_waitcnt vmcnt(6)" ::: "memory");
        else             asm volatile("s_waitcnt vmcnt(0)" ::: "memory");
        __builtin_amdgcn_s_barrier();
        __builtin_amdgcn_sched_barrier(0);
        if (kt + 2 < NT) stage_tile(kt + 2, (kt + 2) % 3);

        const char* Ab = (const char*)lds + (kt % 3) * 49152;
        const char* Bb = Ab + 32768;
        #pragma unroll
        for (int ks = 0; ks < 2; ++ks) {
            const int cb = (ks * 64 + 16 * lg) ^ swzr;
            short8 af[4], bf_[4];
            #pragma unroll
            for (int x = 0; x < 4; ++x)
                af[x] = *reinterpret_cast<const short8*>(Ab + (wm + 16 * x + lq) * 128 + cb);
            #pragma unroll
            for (int y = 0; y < 4; ++y)
                bf_[y] = *reinterpret_cast<const short8*>(Bb + (wn + 16 * y + lq) * 128 + cb);
            __builtin_amdgcn_s_setprio(1);
            #pragma unroll
            for (int x = 0; x < 4; ++x)
                #pragma unroll
                for (int y = 0; y < 4; ++y)
                    acc[x][y] = __builtin_amdgcn_mfma_f32_16x16x32_bf16(af[x], bf_[y], acc[x][y], 0, 0, 0);
            __builtin_amdgcn_s_setprio(0);
        }
    }

    #pragma unroll
    for (int x = 0; x < 4; ++x) {
        #pragma unroll
        for (int y = 0; y < 4; ++y) {
            const int col = bn + wn + 16 * y + lq;
            #pragma unroll
            for (int r = 0; r < 4; ++r) {
                const int row = bm + wm + 16 * x + 4 * lg + r;
                float v = acc[x][y][r];
                if constexpr (BIAS) { if (z == 0) v += bias[col]; }
                if constexpr (RELU) v = fmaxf(v, 0.f);
                if constexpr (OUT == 0) Cf[zoff + (size_t)row * N + col] = v;
                else Cb[zoff + (size_t)row * N + col] = f2bf(v);
            }
        }
    }
}

// ---------------- 256x256 counted-vmcnt + read-ahead GEMM (round-17) ---------
// Round-16 proven schedule + XCD swizzle. OUT==2 grid = 336 blocks:
//   id <  64 : QKV Q-region (tokens >= 512)
//   id < 320 : QKV KV-region
//   id >= 320: rhk = rB @ wrT (2nd input pair A2/B2T), head-major epilogue
// OUT: 1 = bf16 flat.
template<bool BIAS, bool RELU, int OUT>
__global__ __launch_bounds__(512, 2) void gemm256(
    const u16* __restrict__ A, const u16* __restrict__ BT,
    const float* __restrict__ bias, u16* __restrict__ Cb,
    int N, int K, int lda, int ldb, int nbx,
    const u16* __restrict__ A2, const u16* __restrict__ B2T,
    u16* __restrict__ Cb2)
{
    __shared__ u16 lds[2 * 32768];        // 2 x (A 256x64 + B 256x64) = 128 KB
    // T1 chunked XCD swizzle (gridDim.x % 8 == 0 for all users: 336, 256)
    const int id = ((int)blockIdx.x % 8) * ((int)gridDim.x / 8) + (int)blockIdx.x / 8;
    int bm, bn;
    bool isR = false;
    if constexpr (OUT == 2) {             // QKV with Q-skip + fused rhk
        if (id >= 320)     { int j = id - 320; bm = (j >> 2) * 256; bn = (j & 3) * 256;
                             isR = true; A = A2; BT = B2T; }
        else if (id < 64)  { bm = 4096 + (id >> 2) * 256; bn = (id & 3) * 256; }
        else               { int j = id - 64; bm = (j >> 3) * 256; bn = 1024 + (j & 7) * 256; }
    } else {
        bm = (id / nbx) * 256; bn = (id % nbx) * 256;
    }
    const int t = threadIdx.x;            // 0..511
    const int w = t >> 6, l = t & 63, lg = l >> 4, lq = l & 15;
    const int wm = (w >> 2) * 128;        // 2 M-groups of 128
    const int wn = (w & 3) * 64;          // 4 N-groups of 64
    const int srow = t >> 3, slot = t & 7;
    const int gcol = (slot * 16) ^ ((srow & 7) << 4);
    const int swzr = (lq & 7) << 4;

    auto stage_unit = [&](int kt, char* buf, int u) {
        const int k0 = kt * 64;
        if (u < 2) {            // B row-groups {2u, 2u+1}
            #pragma unroll
            for (int i = 0; i < 2; ++i) {
                int g = u * 2 + i;
                gload16((const char*)BT + (((size_t)(bn + g * 64 + srow) * ldb + k0) << 1) + gcol,
                        buf + 32768 + g * 8192 + w * 1024);
            }
        } else {                // A row-groups {u-2, u}: u2={0,2} (mh0), u3={1,3} (mh1)
            #pragma unroll
            for (int i = 0; i < 2; ++i) {
                int g = (u - 2) + i * 2;
                gload16((const char*)A + (((size_t)(bm + g * 64 + srow) * lda + k0) << 1) + gcol,
                        buf + g * 8192 + w * 1024);
            }
        }
    };

    f32x4 acc[8][4];
    #pragma unroll
    for (int m = 0; m < 8; ++m)
        #pragma unroll
        for (int y = 0; y < 4; ++y)
            acc[m][y] = (f32x4){0.f, 0.f, 0.f, 0.f};

    const int NT = K >> 6;
    #pragma unroll
    for (int u = 0; u < 4; ++u) stage_unit(0, (char*)lds, u);

    for (int kt = 0; kt < NT; ++kt) {
        const char* Ab = (const char*)lds + (kt & 1) * 65536;
        const char* Bb = Ab + 32768;
        char* nbuf = (char*)lds + ((kt + 1) & 1) * 65536;
        const bool pf = (kt + 1 < NT);
        const int cb0 = (16 * lg) ^ swzr;
        const int cb1 = (64 + 16 * lg) ^ swzr;

        short8 bk0[4], bk1[4], a00[4], a01[4], a10[4], a11[4];

        // ---- phase 0: (mh0, ks0); reads touch only u0-u2
        asm volatile("s_waitcnt vmcnt(2)" ::: "memory");
        __builtin_amdgcn_s_barrier();
        __builtin_amdgcn_sched_barrier(0);
        #pragma unroll
        for (int y = 0; y < 4; ++y)
            bk0[y] = *reinterpret_cast<const short8*>(Bb + (wn + 16 * y + lq) * 128 + cb0);
        __builtin_amdgcn_sched_barrier(0);
        #pragma unroll
        for (int x = 0; x < 4; ++x)
            a00[x] = *reinterpret_cast<const short8*>(Ab + (wm + 16 * x + lq) * 128 + cb0);
        __builtin_amdgcn_sched_barrier(0);
        #pragma unroll
        for (int y = 0; y < 4; ++y)
            bk1[y] = *reinterpret_cast<const short8*>(Bb + (wn + 16 * y + lq) * 128 + cb1);
        __builtin_amdgcn_sched_barrier(0);
        #pragma unroll
        for (int x = 0; x < 4; ++x)
            a01[x] = *reinterpret_cast<const short8*>(Ab + (wm + 16 * x + lq) * 128 + cb1);
        __builtin_amdgcn_sched_barrier(0);
        if (pf) stage_unit(kt + 1, nbuf, 0);
        asm volatile("s_waitcnt lgkmcnt(8)" ::: "memory");
        __builtin_amdgcn_sched_barrier(0);
        __builtin_amdgcn_s_setprio(1);
        #pragma unroll
        for (int x = 0; x < 4; ++x)
            #pragma unroll
            for (int y = 0; y < 4; ++y)
                acc[x][y] = __builtin_amdgcn_mfma_f32_16x16x32_bf16(a00[x], bk0[y], acc[x][y], 0, 0, 0);
        __builtin_amdgcn_s_setprio(0);

        // ---- phase 1: (mh0, ks1); u3 now resident after this vmcnt
        if (pf) asm volatile("s_waitcnt vmcnt(2)" ::: "memory");
        else    asm volatile("s_waitcnt vmcnt(0)" ::: "memory");
        __builtin_amdgcn_s_barrier();
        __builtin_amdgcn_sched_barrier(0);
        #pragma unroll
        for (int x = 0; x < 4; ++x)
            a10[x] = *reinterpret_cast<const short8*>(Ab + (wm + 64 + 16 * x + lq) * 128 + cb0);
        __builtin_amdgcn_sched_barrier(0);
        #pragma unroll
        for (int x = 0; x < 4; ++x)
            a11[x] = *reinterpret_cast<const short8*>(Ab + (wm + 64 + 16 * x + lq) * 128 + cb1);
        __builtin_amdgcn_sched_barrier(0);
        if (pf) stage_unit(kt + 1, nbuf, 1);
        asm volatile("s_waitcnt lgkmcnt(8)" ::: "memory");
        __builtin_amdgcn_sched_barrier(0);
        __builtin_amdgcn_s_setprio(1);
        #pragma unroll
        for (int x = 0; x < 4; ++x)
            #pragma unroll
            for (int y = 0; y < 4; ++y)
                acc[x][y] = __builtin_amdgcn_mfma_f32_16x16x32_bf16(a01[x], bk1[y], acc[x][y], 0, 0, 0);
        __builtin_amdgcn_s_setprio(0);

        // ---- phase 2: (mh1, ks0)
        __builtin_amdgcn_s_barrier();
        __builtin_amdgcn_sched_barrier(0);
        if (pf) stage_unit(kt + 1, nbuf, 2);
        asm volatile("s_waitcnt lgkmcnt(4)" ::: "memory");
        __builtin_amdgcn_sched_barrier(0);
        __builtin_amdgcn_s_setprio(1);
        #pragma unroll
        for (int x = 0; x < 4; ++x)
            #pragma unroll
            for (int y = 0; y < 4; ++y)
                acc[4 + x][y] = __builtin_amdgcn_mfma_f32_16x16x32_bf16(a10[x], bk0[y], acc[4 + x][y], 0, 0, 0);
        __builtin_amdgcn_s_setprio(0);

        // ---- phase 3: (mh1, ks1)
        __builtin_amdgcn_s_barrier();
        __builtin_amdgcn_sched_barrier(0);
        if (pf) stage_unit(kt + 1, nbuf, 3);
        asm volatile("s_waitcnt lgkmcnt(0)" ::: "memory");
        __builtin_amdgcn_sched_barrier(0);
        __builtin_amdgcn_s_setprio(1);
        #pragma unroll
        for (int x = 0; x < 4; ++x)
            #pragma unroll
            for (int y = 0; y < 4; ++y)
                acc[4 + x][y] = __builtin_amdgcn_mfma_f32_16x16x32_bf16(a11[x], bk1[y], acc[4 + x][y], 0, 0, 0);
        __builtin_amdgcn_s_setprio(0);
    }

    #pragma unroll
    for (int m = 0; m < 8; ++m) {
        #pragma unroll
        for (int y = 0; y < 4; ++y) {
            const int col = bn + wn + 16 * y + lq;
            #pragma unroll
            for (int r = 0; r < 4; ++r) {
                const int row = bm + wm + m * 16 + 4 * lg + r;
                float v = acc[m][y][r];
                if constexpr (BIAS) v += bias[col];
                if constexpr (RELU) v = fmaxf(v, 0.f);
                if constexpr (OUT == 2) {
                    if (isR) {   // rhk head-major [n][row][d]
                        const int nn = (col >> 6) & 15;
                        Cb2[((size_t)nn * 1024 + row) * 64 + (col & 63)] = f2bf(v);
                    } else {     // QKV head-major: row = key*8+b
                        const int part = col >> 10, nn = (col >> 6) & 15;
                        Cb[(size_t)part * HM_PART
                           + ((size_t)((row & 7) * 16 + nn) * 1024 + (row >> 3)) * 64
                           + (col & 63)] = f2bf(v);
                    }
                } else {
                    Cb[(size_t)row * N + col] = f2bf(v);
                }
            }
        }
    }
}

// ---------------- MFMA flash relative attention (round-13 form, proven) ------
__global__ __launch_bounds__(512, 4) void attn_mfma(
    const u16* __restrict__ Hm,      // head-major Q|K|V, parts of [(b,h)][tok][d]
    const u16* __restrict__ Vg,      // bf16 [(b,h)][DH][KLEN]
    const u16* __restrict__ rhm,     // bf16 head-major [h][o][d]
    const float* __restrict__ rwb, const float* __restrict__ rrb,
    u16* __restrict__ vec)           // bf16 [QLEN*BSZ][NH*DH]
{
    const int bnidx = blockIdx.x;                // b*16+n
    const int b = bnidx >> 4;
    const int n = bnidx & 15;
    const int i0 = (3 - blockIdx.y) * 128;       // long blocks first
    const int t = threadIdx.x;
    const int w = t >> 6;                        // 0..7
    const int l = t & 63;
    const int lg = l >> 4, lq = l & 15;
    const int r8 = l >> 3, sl = l & 7;

    const u16* Qh = Hm;
    const u16* Kh = Hm + HM_PART;

    __shared__ u16 Ks[64 * 64];
    __shared__ u16 Vt[64 * 64];
    __shared__ u16 Rs[192 * 64];
    __shared__ u16 SbO[8 * 16 * 84];
    __shared__ u16 Ps[8 * 16 * 64];

    u16* SbW = SbO + w * 16 * 84;
    u16* PsW = Ps + w * 16 * 64;
    const int swzr = (lq & 7) << 4;
    const int stg_swz = (sl * 16) ^ (r8 << 4);
    const int lofs = l * 16;
    const int rbase = 384 - i0;
    const int ntiles = i0 / 64 + 10;

    auto kSrc = [&](int tile) {
        return (const char*)Kh + (((size_t)bnidx * 1024 + (tile << 6) + w * 8 + r8) * 64 << 1) + stg_swz;
    };
    auto vSrc = [&](int tile) {
        return (const char*)Vg + ((((size_t)bnidx * 64 + w * 8 + r8) * KLEN + (tile << 6)) << 1) + stg_swz;
    };
    auto rSrc = [&](int g) {
        int o = rbase + g * 64 + w * 8 + r8;
        o = o > (KLEN - 1) ? (KLEN - 1) : o;
        return (const char*)rhm + (((size_t)n * 1024 + o) * 64 << 1) + stg_swz;
    };

    // Q fragments with 1/sqrt(d)=0.125 folded in
    short8 qw[2], qr[2];
    {
        const size_t qbase = ((size_t)bnidx * 1024 + MLEN + i0 + 16 * w + lq) * 64;
        #pragma unroll
        for (int ks = 0; ks < 2; ++ks) {
            short8 qv = *reinterpret_cast<const short8*>(&Qh[qbase + ks * 32 + 8 * lg]);
            short8 xw, xr;
            #pragma unroll
            for (int e = 0; e < 8; ++e) {
                float f = bf2f((u16)qv[e]);
                int d = ks * 32 + 8 * lg + e;
                xw[e] = (short)f2bf((f + rwb[n * 64 + d]) * 0.125f);
                xr[e] = (short)f2bf((f + rrb[n * 64 + d]) * 0.125f);
            }
            qw[ks] = xw; qr[ks] = xr;
        }
    }

    float m_run = NEGF, l_run = 0.f;
    f32x4 acc[4];
    #pragma unroll
    for (int df = 0; df < 4; ++df) acc[df] = (f32x4){0.f, 0.f, 0.f, 0.f};

    const int s0 = 112 - 16 * w;

    // prologue: tile-0 staging into registers
    u32x4 kreg = *reinterpret_cast<const u32x4*>(kSrc(0));
    u32x4 vreg = *reinterpret_cast<const u32x4*>(vSrc(0));
    u32x4 rr0  = *reinterpret_cast<const u32x4*>(rSrc(0));
    u32x4 rr1  = *reinterpret_cast<const u32x4*>(rSrc(1));
    u32x4 rr2  = *reinterpret_cast<const u32x4*>(rSrc(2));

    for (int tile = 0; tile < ntiles; ++tile) {
        const int j0 = tile << 6;
        __builtin_amdgcn_s_barrier();            // all waves done reading prev tile
        __builtin_amdgcn_sched_barrier(0);
        *reinterpret_cast<u32x4*>((char*)Ks + w * 1024 + lofs) = kreg;
        *reinterpret_cast<u32x4*>((char*)Vt + w * 1024 + lofs) = vreg;
        if (tile == 0) {
            *reinterpret_cast<u32x4*>((char*)Rs + 0 * 8192 + w * 1024 + lofs) = rr0;
            *reinterpret_cast<u32x4*>((char*)Rs + 1 * 8192 + w * 1024 + lofs) = rr1;
            *reinterpret_cast<u32x4*>((char*)Rs + 2 * 8192 + w * 1024 + lofs) = rr2;
        } else {
            *reinterpret_cast<u32x4*>((char*)Rs + ((tile + 2) % 3) * 8192 + w * 1024 + lofs) = rr0;
        }
        if (tile + 1 < ntiles) {
            kreg = *reinterpret_cast<const u32x4*>(kSrc(tile + 1));
            vreg = *reinterpret_cast<const u32x4*>(vSrc(tile + 1));
            rr0  = *reinterpret_cast<const u32x4*>(rSrc(tile + 3));
        }
        asm volatile("s_waitcnt lgkmcnt(0)" ::: "memory");
        __builtin_amdgcn_s_barrier();            // all waves' ds_writes visible
        __builtin_amdgcn_sched_barrier(0);

        const int bmax = i0 + 16 * w + 15 + MLEN - j0;
        if (bmax < 0) continue;                  // per-wave skip; barriers balanced

        __builtin_amdgcn_s_setprio(1);
        #pragma unroll
        for (int ff = 0; ff < 5; ++ff) {
            const int olf = s0 + 16 * ff;
            const int srowb = ((tile + (olf >> 6)) % 3) * 64 + (olf & 63);
            f32x4 d = (f32x4){0.f, 0.f, 0.f, 0.f};
            #pragma unroll
            for (int ks = 0; ks < 2; ++ks) {
                short8 a = *reinterpret_cast<const short8*>(
                    (char*)Rs + (srowb + lq) * 128 + ((ks * 64 + 16 * lg) ^ swzr));
                d = __builtin_amdgcn_mfma_f32_16x16x32_bf16(a, qr[ks], d, 0, 0, 0);
            }
            s16x4 pk;
            #pragma unroll
            for (int r = 0; r < 4; ++r) pk[r] = (short)f2bf(d[r]);
            *reinterpret_cast<s16x4*>(&SbW[lq * 84 + 16 * ff + 4 * lg]) = pk;
        }
        f32x4 dac[4];
        #pragma unroll
        for (int f = 0; f < 4; ++f) {
            f32x4 d = (f32x4){0.f, 0.f, 0.f, 0.f};
            #pragma unroll
            for (int ks = 0; ks < 2; ++ks) {
                short8 a = *reinterpret_cast<const short8*>(
                    (char*)Ks + (16 * f + lq) * 128 + ((ks * 64 + 16 * lg) ^ swzr));
                d = __builtin_amdgcn_mfma_f32_16x16x32_bf16(a, qw[ks], d, 0, 0, 0);
            }
            dac[f] = d;
        }
        __builtin_amdgcn_s_setprio(0);

        const bool fullTile = (i0 + 16 * w + MLEN - j0) >= 63;
        float sv[4][4];
        float mx = NEGF;
        if (fullTile) {
            #pragma unroll
            for (int f = 0; f < 4; ++f)
                #pragma unroll
                for (int r = 0; r < 4; ++r) {
                    int k = 16 * f + 4 * lg + r;
                    float x = dac[f][r] + bf2f(SbW[lq * 84 + k - lq + 15]);
                    sv[f][r] = x;
                    mx = fmaxf(mx, x);
                }
        } else {
            const int bound = i0 + 16 * w + lq + MLEN - j0;
            #pragma unroll
            for (int f = 0; f < 4; ++f)
                #pragma unroll
                for (int r = 0; r < 4; ++r) {
                    int k = 16 * f + 4 * lg + r;
                    float x = (k <= bound)
                        ? dac[f][r] + bf2f(SbW[lq * 84 + k - lq + 15]) : NEGF;
                    sv[f][r] = x;
                    mx = fmaxf(mx, x);
                }
        }
        mx = fmaxf(mx, __shfl_xor(mx, 16));
        mx = fmaxf(mx, __shfl_xor(mx, 32));
        const bool defer = (__all(mx <= m_run + 8.0f) != 0);
        const float m_new = defer ? m_run : fmaxf(m_run, mx);
        float ps = 0.f;
        #pragma unroll
        for (int f = 0; f < 4; ++f) {
            s16x4 pk;
            #pragma unroll
            for (int r = 0; r < 4; ++r) {
                float p = __expf(sv[f][r] - m_new);
                ps += p;
                pk[r] = (short)f2bf(p);
            }
            *reinterpret_cast<s16x4*>(
                (char*)PsW + lq * 128 + (((4 * f + lg) ^ ((lq & 7) << 1)) << 3)) = pk;
        }
        ps += __shfl_xor(ps, 16);
        ps += __shfl_xor(ps, 32);
        if (defer) {
            l_run += ps;
        } else {
            float alpha = __expf(m_run - m_new);
            l_run = l_run * alpha + ps;
            m_run = m_new;
            float alr[4];
            #pragma unroll
            for (int r = 0; r < 4; ++r) alr[r] = __shfl(alpha, 20 * lg + r);
            #pragma unroll
            for (int df = 0; df < 4; ++df)
                #pragma unroll
                for (int r = 0; r < 4; ++r) acc[df][r] *= alr[r];
        }

        __builtin_amdgcn_s_setprio(1);
        #pragma unroll
        for (int df = 0; df < 4; ++df) {
            f32x4 a = acc[df];
            #pragma unroll
            for (int ks = 0; ks < 2; ++ks) {
                short8 pa = *reinterpret_cast<const short8*>(
                    (char*)PsW + lq * 128 + ((ks * 64 + 16 * lg) ^ swzr));
                short8 vb = *reinterpret_cast<const short8*>(
                    (char*)Vt + (16 * df + lq) * 128 + ((ks * 64 + 16 * lg) ^ swzr));
                a = __builtin_amdgcn_mfma_f32_16x16x32_bf16(pa, vb, a, 0, 0, 0);
            }
            acc[df] = a;
        }
        __builtin_amdgcn_s_setprio(0);
    }

    float inv[4];
    #pragma unroll
    for (int r = 0; r < 4; ++r) inv[r] = 1.f / __shfl(l_run, 20 * lg + r);
    #pragma unroll
    for (int df = 0; df < 4; ++df) {
        #pragma unroll
        for (int r = 0; r < 4; ++r) {
            const int il = 16 * w + 4 * lg + r;
            float o = acc[df][r] * inv[r];
            vec[((size_t)((i0 + il) * BSZ + b)) * DM + n * 64 + 16 * df + lq] = f2bf(o);
        }
    }
}

// ---------------- Residual + LayerNorm: fp32 trunk + NRES bf16 partials ------
template<int NRES, bool WB>
__global__ __launch_bounds__(256) void ln_res_kernel(
    const float* __restrict__ x,
    const u16* __restrict__ r0, const u16* __restrict__ r1,
    const float* __restrict__ g, const float* __restrict__ bta,
    float* __restrict__ out, u16* __restrict__ outb)
{
    const int row = blockIdx.x;
    const int t = threadIdx.x;
    const int lane = t & 63, wv = t >> 6;
    __shared__ float red0[4], red1[4];

    const size_t base = (size_t)row * DM + t * 4;
    float4 a = ldg4(&x[base]);
    float v0 = a.x, v1 = a.y, v2 = a.z, v3 = a.w;
    const u16* rs[2] = { r0, r1 };
    #pragma unroll
    for (int s = 0; s < NRES; ++s) {
        uint2 u = *reinterpret_cast<const uint2*>(&rs[s][base]);
        v0 += bf2f((u16)(u.x & 0xffff));
        v1 += bf2f((u16)(u.x >> 16));
        v2 += bf2f((u16)(u.y & 0xffff));
        v3 += bf2f((u16)(u.y >> 16));
    }
    float s = v0 + v1 + v2 + v3;
    #pragma unroll
    for (int o = 32; o; o >>= 1) s += __shfl_xor(s, o);
    if (lane == 0) red0[wv] = s;
    __syncthreads();
    float mu = (red0[0] + red0[1] + red0[2] + red0[3]) * (1.f / DM);
    float d0 = v0 - mu, d1 = v1 - mu, d2 = v2 - mu, d3 = v3 - mu;
    float q = d0*d0 + d1*d1 + d2*d2 + d3*d3;
    #pragma unroll
    for (int o = 32; o; o >>= 1) q += __shfl_xor(q, o);
    if (lane == 0) red1[wv] = q;
    __syncthreads();
    float var = (red1[0] + red1[1] + red1[2] + red1[3]) * (1.f / DM);
    float rsq = rsqrtf(var + 1e-5f);
    float4 gv = ldg4(&g[t * 4]);
    float4 bv = ldg4(&bta[t * 4]);
    float o0 = d0 * rsq * gv.x + bv.x;
    float o1 = d1 * rsq * gv.y + bv.y;
    float o2 = d2 * rsq * gv.z + bv.z;
    float o3 = d3 * rsq * gv.w + bv.w;
    float4 o4 = make_float4(o0, o1, o2, o3);
    *reinterpret_cast<float4*>(&out[base]) = o4;
    if constexpr (WB) {
        u16 ob[4] = { f2bf(o0), f2bf(o1), f2bf(o2), f2bf(o3) };
        *reinterpret_cast<uint2*>(&outb[base]) = *reinterpret_cast<uint2*>(ob);
    }
}

// ---------------- launch ------------------------------------------------------
extern "C" void kernel_launch(void* const* d_in, const int* in_sizes, int n_in,
                              void* d_out, int out_size, void* d_ws, size_t ws_size,
                              hipStream_t stream) {
    const float* w     = (const float*)d_in[0];
    const float* r     = (const float*)d_in[1];
    const float* mems  = (const float*)d_in[2];
    const float* w_qkv = (const float*)d_in[3];
    const float* w_r   = (const float*)d_in[4];
    const float* w_o   = (const float*)d_in[5];
    const float* rwb   = (const float*)d_in[6];
    const float* rrb   = (const float*)d_in[7];
    const float* ln1g  = (const float*)d_in[8];
    const float* ln1b  = (const float*)d_in[9];
    const float* ffw1  = (const float*)d_in[10];
    const float* ffb1  = (const float*)d_in[11];
    const float* ffw2  = (const float*)d_in[12];
    const float* ffb2  = (const float*)d_in[13];
    const float* ln2g  = (const float*)d_in[14];
    const float* ln2b  = (const float*)d_in[15];
    (void)in_sizes; (void)n_in; (void)out_size; (void)ws_size;

    char* p = (char*)d_ws;
    auto alloc = [&](size_t bytes) { char* q = p; p += (bytes + 255) & ~(size_t)255; return q; };
    u16* catB   = (u16*)alloc((size_t)8192 * 1024 * 2);   // reused as Vg after QKV GEMM
    u16* rB     = (u16*)alloc((size_t)1024 * 1024 * 2);
    u16* qkvT   = (u16*)alloc((size_t)3072 * 1024 * 2);
    u16* wrT    = (u16*)alloc((size_t)1024 * 1024 * 2);
    u16* woT    = (u16*)alloc((size_t)1024 * 1024 * 2);
    u16* f1T    = (u16*)alloc((size_t)4096 * 1024 * 2);
    u16* f2T    = (u16*)alloc((size_t)1024 * 4096 * 2);
    u16* headsHm= (u16*)alloc((size_t)3 * HM_PART * 2);   // reused as ff2 partials
    u16* rhkHm  = (u16*)alloc((size_t)1024 * 1024 * 2);
    u16* vec    = (u16*)alloc((size_t)4096 * 1024 * 2);
    u16* hB     = (u16*)alloc((size_t)4096 * 1024 * 2);
    u16* ff1    = (u16*)alloc((size_t)4096 * 4096 * 2);   // doubles as attn_out partials
    float* hF   = (float*)alloc((size_t)4096 * 1024 * 4);

    u16* Vg = catB;
    u16* aoP = ff1;                       // attn_out: 2 bf16 partials
    u16* f2P = headsHm;                   // ff2: 2 bf16 partials
    const size_t PSTR = (size_t)4096 * 1024;
    float* outp = (float*)d_out;

    // fused casts + fused weight transposes
    cast_all<<<9216, 256, 0, stream>>>(mems, w, r, catB, rB);
    transpose_all<<<13312, 256, 0, stream>>>(w_qkv, qkvT, w_r, wrT, w_o, woT,
                                             ffw1, f1T, ffw2, f2T);

    // 1. heads = cat @ w_qkv (Q-skip) + FUSED rhk = r @ w_r (blocks 320-335)
    gemm256<false, false, 2><<<336, 512, 0, stream>>>(
        catB, qkvT, nullptr, headsHm, 3072, 1024, 1024, 1024, 0, rB, wrT, rhkHm);
    // 2. V transpose (catB dead -> Vg aliases it); reads V_hm part
    v_transpose<<<dim3(128, 16), 256, 0, stream>>>(headsHm + 2 * HM_PART, Vg);
    // 3. attention (T14 reg-staged prefetch)
    attn_mfma<<<dim3(BSZ * NH, QLEN / 128), 512, 0, stream>>>(
        headsHm, Vg, rhkHm, rwb, rrb, vec);
    // 4. attn_out = vec @ w_o, split-K x2 (128^2 kernel, bf16 partials)
    gemm_mfma<false, false, 1><<<dim3(8, 32, 2), 256, 0, stream>>>(
        vec, woT, nullptr, nullptr, aoP, 4096, 1024, 512, 1024, 1024);
    // 5. h = LN(w + ao0 + ao1), keep fp32 + bf16
    ln_res_kernel<2, true><<<4096, 256, 0, stream>>>(
        w, aoP, aoP + PSTR, ln1g, ln1b, hF, hB);
    // 6. ff1 = relu(h @ ff_w1 + b1)  (read-ahead 256^2 + XCD swizzle)
    gemm256<true, true, 1><<<256, 512, 0, stream>>>(
        hB, f1T, ffb1, ff1, 4096, 1024, 1024, 1024, 16, nullptr, nullptr, nullptr);
    // 7. ff2 = ff1 @ ff_w2 + b2, split-K x2 (proven deep kernel, bf16 partials)
    gemm_deep<true, false, 1><<<dim3(8, 16, 2), 512, 0, stream>>>(
        ff1, f2T, ffb2, nullptr, f2P, 4096, 1024, 2048, 4096, 4096);
    // 8. out = LN(h + ff2a + ff2b)
    ln_res_kernel<2, false><<<4096, 256, 0, stream>>>(
        hF, f2P, f2P + PSTR, ln2g, ln2b, outp, nullptr);
}